// Round 1
// 322.134 us; speedup vs baseline: 1.0181x; 1.0181x over previous
//
#include <hip/hip_runtime.h>

#define B_   2
#define S_   2048
#define H_   2048
#define NH_  32
#define NKV_ 8
#define HD_  64
#define ROWS (B_*S_)   // 4096
#define MEXP 20.0f

typedef unsigned short u16;
typedef __bf16 bf16x8_t __attribute__((ext_vector_type(8)));
typedef float  f32x4_t  __attribute__((ext_vector_type(4)));

__device__ __forceinline__ u16 f2bf(float f) {
  union { float f; unsigned u; } v; v.f = f;
  unsigned u = v.u;
  u += 0x7FFFu + ((u >> 16) & 1u);
  return (u16)(u >> 16);
}

// async global->LDS, 16B per lane. LDS dest = wave-uniform base + lane*16.
__device__ __forceinline__ void gload16(const u16* g, u16* l) {
  __builtin_amdgcn_global_load_lds((const __attribute__((address_space(1))) void*)g,
                                   (__attribute__((address_space(3))) void*)l, 16, 0, 0);
}

// ---------------- elementwise converts / prep ----------------

__global__ void cvt_bf16(const float* __restrict__ src, u16* __restrict__ dst, int n4) {
  int i = blockIdx.x * 256 + threadIdx.x;
  if (i >= n4) return;
  float4 v = reinterpret_cast<const float4*>(src)[i];
  ushort4 o;
  o.x = f2bf(v.x); o.y = f2bf(v.y); o.z = f2bf(v.z); o.w = f2bf(v.w);
  reinterpret_cast<ushort4*>(dst)[i] = o;
}

// merged transpose of Wq|Wk|Wv -> Wqkvt [3072][2048] bf16. grid (96,64),(32,8)
__global__ void transpose_wqkv(const float* __restrict__ Wq, const float* __restrict__ Wk,
                               const float* __restrict__ Wv, u16* __restrict__ dst) {
  __shared__ float t[32][33];
  const int k0  = blockIdx.y * 32;
  const int n0g = blockIdx.x * 32;
  const float* src; int N, n0;
  if (n0g < 2048)      { src = Wq; N = 2048; n0 = n0g; }
  else if (n0g < 2560) { src = Wk; N = 512;  n0 = n0g - 2048; }
  else                 { src = Wv; N = 512;  n0 = n0g - 2560; }
  const int tx = threadIdx.x, ty = threadIdx.y;
#pragma unroll
  for (int i = 0; i < 32; i += 8)
    t[ty + i][tx] = src[(size_t)(k0 + ty + i) * N + n0 + tx];
  __syncthreads();
#pragma unroll
  for (int i = 0; i < 32; i += 8)
    dst[(size_t)(n0g + ty + i) * 2048 + k0 + tx] = f2bf(t[tx][ty + i]);
}

__global__ void transpose_w(const float* __restrict__ src, u16* __restrict__ dst, int N) {
  __shared__ float t[32][33];
  const int k0 = blockIdx.y * 32;
  const int n0 = blockIdx.x * 32;
  const int tx = threadIdx.x, ty = threadIdx.y;
#pragma unroll
  for (int i = 0; i < 32; i += 8)
    t[ty + i][tx] = src[(size_t)(k0 + ty + i) * N + n0 + tx];
  __syncthreads();
#pragma unroll
  for (int i = 0; i < 32; i += 8)
    dst[(size_t)(n0 + ty + i) * 2048 + k0 + tx] = f2bf(t[tx][ty + i]);
}

// cos/sin tables [ROWS][32] f32 (d < 32 only; d+32 shares values).
__global__ void cossin_k(const int* __restrict__ pos,
                         float* __restrict__ cosb, float* __restrict__ sinb) {
  int t = blockIdx.x * 256 + threadIdx.x;   // row*32 + d
  int row = t >> 5, d = t & 31;
  int sec = (d < 16) ? 0 : 1;
  float p = (float)pos[sec * ROWS + row];
  float inv_freq = powf(1.0e6f, -(float)d * (1.0f / 32.0f));
  float fr = p * inv_freq;
  float s, c;
  sincosf(fr, &s, &c);
  cosb[t] = c;
  sinb[t] = s;
}

// ---------------- 256x256 BK=64 8-phase pipelined GEMM (T2+T3+T4+T5) ----------------
// 8 waves (2M x 4N), per-wave 128x64 output, acc[8][4]. A/B double-buffered
// half-tile slots; per K-tile: ph0 reads all B frags + A(m0,1) and stages
// A(kt+1); ph1/ph2 read A(m2,3)/(m4,5) and stage B0/B1(kt+2); ph3 reads
// A(m6,7), then single counted vmcnt(4) (0 only at tail) + barrier.
// LDS chunk swizzle: chunk ^= (row&7); global source pre-swizzled (rule 21).
// MODE 0: fused bias+mRoPE QKV epilogue. MODE 1: plain f32 store.

#define BAR() { __builtin_amdgcn_s_barrier(); __builtin_amdgcn_sched_barrier(0); }

#define STG(G, L, RB, h, kt) { \
    const u16* g_ = (G) + (size_t)((RB) + (h) * 128 + srow) * 2048 + (kt) * 64 + sc8; \
    gload16(g_,             (L) + (h) * 8192 + sldo);       \
    gload16(g_ + 8 * 2048,  (L) + (h) * 8192 + sldo + 512); }

#define LDAF(mm) \
    af[0][0] = *reinterpret_cast<const bf16x8_t*>(Asp + rowxA + (mm) * 1024 + cof0); \
    af[0][1] = *reinterpret_cast<const bf16x8_t*>(Asp + rowxA + (mm) * 1024 + cof1); \
    af[1][0] = *reinterpret_cast<const bf16x8_t*>(Asp + rowxA + (mm) * 1024 + 1024 + cof0); \
    af[1][1] = *reinterpret_cast<const bf16x8_t*>(Asp + rowxA + (mm) * 1024 + 1024 + cof1);

#define MFMA8(mb) \
    _Pragma("unroll") \
    for (int n = 0; n < 4; ++n) { \
      acc[(mb)][n]     = __builtin_amdgcn_mfma_f32_16x16x32_bf16(af[0][0], bfr[n][0], acc[(mb)][n], 0, 0, 0); \
      acc[(mb)][n]     = __builtin_amdgcn_mfma_f32_16x16x32_bf16(af[0][1], bfr[n][1], acc[(mb)][n], 0, 0, 0); \
      acc[(mb) + 1][n] = __builtin_amdgcn_mfma_f32_16x16x32_bf16(af[1][0], bfr[n][0], acc[(mb) + 1][n], 0, 0, 0); \
      acc[(mb) + 1][n] = __builtin_amdgcn_mfma_f32_16x16x32_bf16(af[1][1], bfr[n][1], acc[(mb) + 1][n], 0, 0, 0); \
    }

template <int MODE>
__global__ __launch_bounds__(512, 2) void gemm256(
    const u16* __restrict__ A, const u16* __restrict__ Bt,
    const float* __restrict__ bq, const float* __restrict__ bk, const float* __restrict__ bv,
    const float* __restrict__ cosb, const float* __restrict__ sinb,
    u16* __restrict__ Qb, u16* __restrict__ Kb, u16* __restrict__ Vtmp,
    float* __restrict__ Cout, int Nout) {
  const int m0 = blockIdx.x * 256;
  const int n0 = blockIdx.y * 256;
  __shared__ __align__(16) u16 As[2][16384];   // 2 x 32KB (256 rows x 64 cols)
  __shared__ __align__(16) u16 Bs[2][16384];   // 2 x 32KB
  const int tid  = threadIdx.x;
  const int lane = tid & 63;
  const int wv   = tid >> 6;        // 0..7
  const int wr   = wv >> 2;         // 0..1  (M half)
  const int wc   = wv & 3;          // 0..3  (N quarter)
  const int ln   = lane & 15;
  const int quad = lane >> 4;

  // staging geometry: per half-tile (128 rows x 64 cols = 16KB), wave slice is
  // 16 rows; call j covers 8 rows. LDS dest linear; global source inverse-swizzled.
  const int srow = wv * 16 + (lane >> 3);            // row within half (j adds 8)
  const int sc8  = ((lane & 7) ^ (lane >> 3)) * 8;   // pre-swizzled k-chunk (u16)
  const int sldo = wv * 1024;                        // u16 offset of wave slice

  // ds_read geometry: row r, chunk c -> u16 off r*64 + (c ^ (r&7))*8; r&7 == ln&7.
  const int rowxA = (wr * 128 + ln) * 64;
  const int rowxB = (wc * 64  + ln) * 64;
  const int cof0  = ((quad    ) ^ (ln & 7)) * 8;     // kk=0 chunk = quad
  const int cof1  = ((quad ^ 4) ^ (ln & 7)) * 8;     // kk=1 chunk = 4+quad

  f32x4_t acc[8][4];
#pragma unroll
  for (int i = 0; i < 8; i++)
#pragma unroll
    for (int j = 0; j < 4; j++)
      acc[i][j] = (f32x4_t){0.f, 0.f, 0.f, 0.f};

  // prologue: A(0), B(0), B(1). vmcnt(4) -> A(0),B(0) landed, B(1) in flight.
  STG(A,  As[0], m0, 0, 0); STG(A,  As[0], m0, 1, 0);
  STG(Bt, Bs[0], n0, 0, 0); STG(Bt, Bs[0], n0, 1, 0);
  STG(Bt, Bs[1], n0, 0, 1); STG(Bt, Bs[1], n0, 1, 1);
  asm volatile("s_waitcnt vmcnt(4)" ::: "memory");
  BAR();

  for (int kt = 0; kt < 32; ++kt) {
    const int par = kt & 1;
    const u16* Asp = As[par];
    const u16* Bsp = Bs[par];
    u16* Asn = As[par ^ 1];
    u16* Bsn = Bs[par];               // B(kt+2) has same parity as B(kt)
    bf16x8_t bfr[4][2], af[2][2];

    // ---------- phase 0: all B frags + A(m0,m1); stage A(kt+1) ----------
#pragma unroll
    for (int n = 0; n < 4; ++n) {
      bfr[n][0] = *reinterpret_cast<const bf16x8_t*>(Bsp + rowxB + n * 1024 + cof0);
      bfr[n][1] = *reinterpret_cast<const bf16x8_t*>(Bsp + rowxB + n * 1024 + cof1);
    }
    LDAF(0);
    if (kt + 1 < 32) { STG(A, Asn, m0, 0, kt + 1); STG(A, Asn, m0, 1, kt + 1); }
    BAR();
    __builtin_amdgcn_s_setprio(1);
    MFMA8(0);
    __builtin_amdgcn_s_setprio(0);
    BAR();

    // ---------- phase 1: A(m2,m3); stage B half0 (kt+2) ----------
    LDAF(2);
    if (kt + 2 < 32) { STG(Bt, Bsn, n0, 0, kt + 2); }
    BAR();
    __builtin_amdgcn_s_setprio(1);
    MFMA8(2);
    __builtin_amdgcn_s_setprio(0);
    BAR();

    // ---------- phase 2: A(m4,m5); stage B half1 (kt+2) ----------
    LDAF(4);
    if (kt + 2 < 32) { STG(Bt, Bsn, n0, 1, kt + 2); }
    BAR();
    __builtin_amdgcn_s_setprio(1);
    MFMA8(4);
    __builtin_amdgcn_s_setprio(0);
    BAR();

    // ---------- phase 3: A(m6,m7); counted vmcnt drains next tile ----------
    LDAF(6);
    BAR();
    __builtin_amdgcn_s_setprio(1);
    MFMA8(6);
    __builtin_amdgcn_s_setprio(0);
    if (kt + 2 < 32) { asm volatile("s_waitcnt vmcnt(4)" ::: "memory"); }
    else             { asm volatile("s_waitcnt vmcnt(0)" ::: "memory"); }
    BAR();
  }

  if constexpr (MODE == 0) {
    const int colbase = n0 + wc * 64;   // multiple of 64 -> one head per wave
    if (n0 < 2048) {
      const int hq = colbase >> 6;
#pragma unroll
      for (int i = 0; i < 8; i++) {
        int rw0 = m0 + wr * 128 + i * 16 + quad * 4;
#pragma unroll
        for (int j = 0; j < 2; j++) {
          int d = j * 16 + ln;     // < 32
          float b0 = bq[colbase + d];
          float b1 = bq[colbase + d + 32];
#pragma unroll
          for (int r = 0; r < 4; r++) {
            int row = rw0 + r;
            float c  = cosb[row * 32 + d];
            float sn = sinb[row * 32 + d];
            float v0 = acc[i][j][r]     + b0;
            float v1 = acc[i][j + 2][r] + b1;
            int bb = row >> 11, s = row & (S_ - 1);
            size_t base = ((size_t)(bb * NH_ + hq) * S_ + s) * HD_;
            Qb[base + d]      = f2bf((v0 * c - v1 * sn) * 0.125f);
            Qb[base + d + 32] = f2bf((v1 * c + v0 * sn) * 0.125f);
          }
        }
      }
    } else if (n0 < 2560) {
      const int kh = (colbase - 2048) >> 6;
#pragma unroll
      for (int i = 0; i < 8; i++) {
        int rw0 = m0 + wr * 128 + i * 16 + quad * 4;
#pragma unroll
        for (int j = 0; j < 2; j++) {
          int d = j * 16 + ln;
          float b0 = bk[(colbase - 2048) + d];
          float b1 = bk[(colbase - 2048) + d + 32];
#pragma unroll
          for (int r = 0; r < 4; r++) {
            int row = rw0 + r;
            float c  = cosb[row * 32 + d];
            float sn = sinb[row * 32 + d];
            float v0 = acc[i][j][r]     + b0;
            float v1 = acc[i][j + 2][r] + b1;
            int bb = row >> 11, s = row & (S_ - 1);
            size_t base = ((size_t)(bb * NKV_ + kh) * S_ + s) * HD_;
            Kb[base + d]      = f2bf(v0 * c - v1 * sn);
            Kb[base + d + 32] = f2bf(v1 * c + v0 * sn);
          }
        }
      }
    } else {
#pragma unroll
      for (int i = 0; i < 8; i++) {
        int rw0 = m0 + wr * 128 + i * 16 + quad * 4;
#pragma unroll
        for (int j = 0; j < 4; j++) {
          int cv = colbase - 2560 + j * 16 + ln;
          float bvv = bv[cv];
#pragma unroll
          for (int r = 0; r < 4; r++)
            Vtmp[(size_t)(rw0 + r) * 512 + cv] = f2bf(acc[i][j][r] + bvv);
        }
      }
    }
  } else {
#pragma unroll
    for (int i = 0; i < 8; i++) {
      int row = m0 + wr * 128 + i * 16 + quad * 4;
#pragma unroll
      for (int j = 0; j < 4; j++) {
        int col = n0 + wc * 64 + j * 16 + ln;
        float* cp = Cout + (size_t)row * Nout + col;
#pragma unroll
        for (int r = 0; r < 4; r++)
          cp[(size_t)r * Nout] = acc[i][j][r];
      }
    }
  }
}

// V^T with kv-permuted columns from bf16 Vtmp [4096][512].
__global__ void prep_v(const u16* __restrict__ Vtmp, u16* __restrict__ Vt) {
  __shared__ u16 tile[64][65];
  const int sb  = blockIdx.x * 64;
  const int bk  = blockIdx.y;
  const int b   = bk >> 3, kvh = bk & 7;
  const int tx  = threadIdx.x & 63;
  const int ty  = threadIdx.x >> 6;   // 0..3
  const u16* src = Vtmp + (size_t)(b * 2048 + sb) * 512 + kvh * 64;
#pragma unroll
  for (int i = ty; i < 64; i += 4)
    tile[i][tx] = src[(size_t)i * 512 + tx];
  __syncthreads();
  const int sp = sb + (tx & 15) * 4 + (tx >> 4);   // permuted col
  u16* dst = Vt + (size_t)(b * NKV_ + kvh) * HD_ * (size_t)S_;
#pragma unroll
  for (int j = ty; j < 64; j += 4)
    dst[(size_t)j * S_ + sp] = tile[tx][j];
}

// ---------------- causal GQA flash attention (v6: Br=32, LDS-staged K/V) ----------------
__global__ __launch_bounds__(256, 2) void flash_attn(
    const u16* __restrict__ Qb, const u16* __restrict__ Kb, const u16* __restrict__ Vt,
    u16* __restrict__ Og) {
  const int u    = blockIdx.x;        // 0..31
  const int bk   = blockIdx.y;
  const int b    = bk >> 3;
  const int kvh  = bk & 7;
  const int tid  = threadIdx.x;
  const int wv   = tid >> 6;
  const int h    = kvh * 4 + wv;
  const int lane = tid & 63;
  const int ln   = lane & 15;
  const int quad = lane >> 4;

  __shared__ __align__(16) u16 Kl[2][64 * 64];
  __shared__ __align__(16) u16 Vl[2][64 * 64];
  __shared__ __align__(16) u16 Plds[4][2][16][72];

  const u16* Qbase = Qb + ((size_t)(b * NH_ + h) * S_) * HD_;
  const u16* Kbase = Kb + ((size_t)(b * NKV_ + kvh) * S_) * HD_;
  const u16* Vbase = Vt + ((size_t)(b * NKV_ + kvh) * HD_) * S_;

  const int j0 = wv * 2, j1 = wv * 2 + 1;
  const int p0 = j0 * 64 + lane,  p1 = j1 * 64 + lane;
  const int r0 = p0 >> 3,  c0 = (p0 & 7) ^ (r0 & 7);
  const int r1 = p1 >> 3,  c1 = (p1 & 7) ^ (r1 & 7);

  const int sw  = ln & 7;
  const int ck0 = quad ^ sw;
  const int ck1 = ck0 ^ 4;

  const int tlist[2] = {u, 63 - u};

  for (int ti = 0; ti < 2; ++ti) {
    const int t = tlist[ti];
    const int qrow0 = t * 32;

    bf16x8_t qf[2][2];
#pragma unroll
    for (int mt = 0; mt < 2; mt++) {
      qf[mt][0] = *reinterpret_cast<const bf16x8_t*>(
          Qbase + (size_t)(qrow0 + mt * 16 + ln) * HD_ + quad * 8);
      qf[mt][1] = *reinterpret_cast<const bf16x8_t*>(
          Qbase + (size_t)(qrow0 + mt * 16 + ln) * HD_ + 32 + quad * 8);
    }

    f32x4_t O[2][4];
#pragma unroll
    for (int mt = 0; mt < 2; mt++)
#pragma unroll
      for (int dt = 0; dt < 4; dt++)
        O[mt][dt] = (f32x4_t){0.f, 0.f, 0.f, 0.f};
    float l[2][4];
#pragma unroll
    for (int mt = 0; mt < 2; mt++)
#pragma unroll
      for (int r = 0; r < 4; r++) l[mt][r] = 0.f;

    const int nsteps = t / 2 + 1;

    __syncthreads();   // all waves done reading buffers (prev tile)
    gload16(Kbase + (size_t)r0 * HD_ + c0 * 8, &Kl[0][j0 * 512]);
    gload16(Kbase + (size_t)r1 * HD_ + c1 * 8, &Kl[0][j1 * 512]);
    gload16(Vbase + (size_t)r0 * S_ + c0 * 8,  &Vl[0][j0 * 512]);
    gload16(Vbase + (size_t)r1 * S_ + c1 * 8,  &Vl[0][j1 * 512]);

    for (int step = 0; step < nsteps; ++step) {
      const int cur = step & 1;
      const int kv0 = step * 64;
      __syncthreads();   // drains vmcnt -> buf[cur] ready; buf[cur^1] readers done

      if (step + 1 < nsteps) {
        const int nb  = cur ^ 1;
        const int nkv = kv0 + 64;
        gload16(Kbase + (size_t)(nkv + r0) * HD_ + c0 * 8, &Kl[nb][j0 * 512]);
        gload16(Kbase + (size_t)(nkv + r1) * HD_ + c1 * 8, &Kl[nb][j1 * 512]);
        gload16(Vbase + (size_t)r0 * S_ + nkv + c0 * 8,    &Vl[nb][j0 * 512]);
        gload16(Vbase + (size_t)r1 * S_ + nkv + c1 * 8,    &Vl[nb][j1 * 512]);
      }

      const u16* Kc = Kl[cur];
      const u16* Vc = Vl[cur];

      bf16x8_t kf0[4], kf1[4];
#pragma unroll
      for (int kt = 0; kt < 4; kt++) {
        const u16* rp = Kc + (kt * 16 + ln) * 64;
        kf0[kt] = *reinterpret_cast<const bf16x8_t*>(rp + ck0 * 8);
        kf1[kt] = *reinterpret_cast<const bf16x8_t*>(rp + ck1 * 8);
      }
      f32x4_t s[2][4];
#pragma unroll
      for (int mt = 0; mt < 2; mt++)
#pragma unroll
        for (int kt = 0; kt < 4; kt++) {
          f32x4_t acc = (f32x4_t){0.f, 0.f, 0.f, 0.f};
          acc = __builtin_amdgcn_mfma_f32_16x16x32_bf16(qf[mt][0], kf0[kt], acc, 0, 0, 0);
          acc = __builtin_amdgcn_mfma_f32_16x16x32_bf16(qf[mt][1], kf1[kt], acc, 0, 0, 0);
          s[mt][kt] = acc;
        }

      bf16x8_t vf0[4], vf1[4];
#pragma unroll
      for (int dt = 0; dt < 4; dt++) {
        const u16* rp = Vc + (dt * 16 + ln) * 64;
        vf0[dt] = *reinterpret_cast<const bf16x8_t*>(rp + ck0 * 8);
        vf1[dt] = *reinterpret_cast<const bf16x8_t*>(rp + ck1 * 8);
      }

      if (kv0 + 63 > qrow0) {
#pragma unroll
        for (int mt = 0; mt < 2; mt++)
#pragma unroll
          for (int kt = 0; kt < 4; kt++)
#pragma unroll
            for (int r = 0; r < 4; r++) {
              int rowg = qrow0 + mt * 16 + quad * 4 + r;
              if (kv0 + kt * 16 + ln > rowg) s[mt][kt][r] = -1e30f;
            }
      }

#pragma unroll
      for (int mt = 0; mt < 2; mt++)
#pragma unroll
        for (int r = 0; r < 4; r++) {
          float p0f = __expf(s[mt][0][r] - MEXP);
          float p1f = __expf(s[mt][1][r] - MEXP);
          float p2f = __expf(s[mt][2][r] - MEXP);
          float p3f = __expf(s[mt][3][r] - MEXP);
          l[mt][r] += (p0f + p1f) + (p2f + p3f);
          ushort4 pk;   // truncation pack (bias cancels in O/l)
          pk.x = (u16)(__float_as_uint(p0f) >> 16);
          pk.y = (u16)(__float_as_uint(p1f) >> 16);
          pk.z = (u16)(__float_as_uint(p2f) >> 16);
          pk.w = (u16)(__float_as_uint(p3f) >> 16);
          *reinterpret_cast<ushort4*>(&Plds[wv][mt][quad * 4 + r][ln * 4]) = pk;
        }

#pragma unroll
      for (int mt = 0; mt < 2; mt++) {
        bf16x8_t pf0 = *reinterpret_cast<const bf16x8_t*>(&Plds[wv][mt][ln][quad * 8]);
        bf16x8_t pf1 = *reinterpret_cast<const bf16x8_t*>(&Plds[wv][mt][ln][32 + quad * 8]);
#pragma unroll
        for (int dt = 0; dt < 4; dt++) {
          O[mt][dt] = __builtin_amdgcn_mfma_f32_16x16x32_bf16(pf0, vf0[dt], O[mt][dt], 0, 0, 0);
          O[mt][dt] = __builtin_amdgcn_mfma_f32_16x16x32_bf16(pf1, vf1[dt], O[mt][dt], 0, 0, 0);
        }
      }
    }

#pragma unroll
    for (int mt = 0; mt < 2; mt++)
#pragma unroll
      for (int r = 0; r < 4; r++) {
        float lv = l[mt][r];
        lv += __shfl_xor(lv, 1);
        lv += __shfl_xor(lv, 2);
        lv += __shfl_xor(lv, 4);
        lv += __shfl_xor(lv, 8);
        float inv = 1.0f / lv;
        int srow = qrow0 + mt * 16 + quad * 4 + r;
        size_t base = ((size_t)b * S_ + srow) * (size_t)(NH_ * HD_) + h * HD_;
#pragma unroll
        for (int dt = 0; dt < 4; dt++)
          Og[base + dt * 16 + ln] = f2bf(O[mt][dt][r] * inv);
      }
  }
}

// ---------------- launch ----------------

extern "C" void kernel_launch(void* const* d_in, const int* in_sizes, int n_in,
                              void* d_out, int out_size, void* d_ws, size_t ws_size,
                              hipStream_t stream) {
  const float* x  = (const float*)d_in[0];
  const int*   pos = (const int*)d_in[1];
  const float* Wq = (const float*)d_in[2];
  const float* bq = (const float*)d_in[3];
  const float* Wk = (const float*)d_in[4];
  const float* bk = (const float*)d_in[5];
  const float* Wv = (const float*)d_in[6];
  const float* bv = (const float*)d_in[7];
  const float* Wo = (const float*)d_in[8];
  float* out = (float*)d_out;

  char* ws = (char*)d_ws;
  u16*   xb    = (u16*)(ws);                     // [4096][2048] bf16   16.8MB
  u16*   Wqkvt = (u16*)(ws + 16777216);          // [3072][2048] bf16   12.6MB
  u16*   Wot   = (u16*)(ws + 29360128);          // [2048][2048] bf16    8.4MB
  float* cosb  = (float*)(ws + 37748736);        // [4096][32] f32
  float* sinb  = (float*)(ws + 38797312);        // [4096][32] f32
  u16*   Qb    = (u16*)(ws + 39845888);          // [B][NH][S][HD]      16.8MB
  u16*   Kb    = (u16*)(ws + 56623104);          // [B][NKV][S][HD]      4.2MB
  u16*   Vtmp  = (u16*)(ws + 60817408);          // [4096][512] bf16     4.2MB
  u16*   Vt    = (u16*)(ws + 65011712);          // [B][NKV][HD][S]      4.2MB (kv-permuted)
  u16*   Og    = (u16*)(ws + 69206016);          // [4096][2048] bf16   16.8MB

  cvt_bf16<<<ROWS * H_ / 4 / 256, 256, 0, stream>>>(x, xb, ROWS * H_ / 4);
  transpose_wqkv<<<dim3(96, 64), dim3(32, 8), 0, stream>>>(Wq, Wk, Wv, Wqkvt);
  transpose_w<<<dim3(64, 64), dim3(32, 8), 0, stream>>>(Wo, Wot, 2048);
  cossin_k<<<ROWS * 32 / 256, 256, 0, stream>>>(pos, cosb, sinb);

  gemm256<0><<<dim3(16, 12), 512, 0, stream>>>(xb, Wqkvt, bq, bk, bv, cosb, sinb,
                                               Qb, Kb, Vtmp, nullptr, 0);

  prep_v<<<dim3(32, 16), 256, 0, stream>>>(Vtmp, Vt);

  flash_attn<<<dim3(32, 16), 256, 0, stream>>>(Qb, Kb, Vt, Og);

  gemm256<1><<<dim3(16, 8), 512, 0, stream>>>(Og, Wot, nullptr, nullptr, nullptr,
                                              nullptr, nullptr, nullptr, nullptr, nullptr,
                                              out, 2048);
}

// Round 2
// 311.382 us; speedup vs baseline: 1.0532x; 1.0345x over previous
//
#include <hip/hip_runtime.h>

#define B_   2
#define S_   2048
#define H_   2048
#define NH_  32
#define NKV_ 8
#define HD_  64
#define ROWS (B_*S_)   // 4096
#define MEXP 20.0f

typedef unsigned short u16;
typedef __bf16 bf16x8_t __attribute__((ext_vector_type(8)));
typedef float  f32x4_t  __attribute__((ext_vector_type(4)));

__device__ __forceinline__ u16 f2bf(float f) {
  union { float f; unsigned u; } v; v.f = f;
  unsigned u = v.u;
  u += 0x7FFFu + ((u >> 16) & 1u);
  return (u16)(u >> 16);
}

// async global->LDS, 16B per lane. LDS dest = wave-uniform base + lane*16.
__device__ __forceinline__ void gload16(const u16* g, u16* l) {
  __builtin_amdgcn_global_load_lds((const __attribute__((address_space(1))) void*)g,
                                   (__attribute__((address_space(3))) void*)l, 16, 0, 0);
}

// ---------------- elementwise converts / prep ----------------

__global__ void cvt_bf16(const float* __restrict__ src, u16* __restrict__ dst, int n4) {
  int i = blockIdx.x * 256 + threadIdx.x;
  if (i >= n4) return;
  float4 v = reinterpret_cast<const float4*>(src)[i];
  ushort4 o;
  o.x = f2bf(v.x); o.y = f2bf(v.y); o.z = f2bf(v.z); o.w = f2bf(v.w);
  reinterpret_cast<ushort4*>(dst)[i] = o;
}

// merged transpose of Wq|Wk|Wv -> Wqkvt [3072][2048] bf16. grid (96,64),(32,8)
__global__ void transpose_wqkv(const float* __restrict__ Wq, const float* __restrict__ Wk,
                               const float* __restrict__ Wv, u16* __restrict__ dst) {
  __shared__ float t[32][33];
  const int k0  = blockIdx.y * 32;
  const int n0g = blockIdx.x * 32;
  const float* src; int N, n0;
  if (n0g < 2048)      { src = Wq; N = 2048; n0 = n0g; }
  else if (n0g < 2560) { src = Wk; N = 512;  n0 = n0g - 2048; }
  else                 { src = Wv; N = 512;  n0 = n0g - 2560; }
  const int tx = threadIdx.x, ty = threadIdx.y;
#pragma unroll
  for (int i = 0; i < 32; i += 8)
    t[ty + i][tx] = src[(size_t)(k0 + ty + i) * N + n0 + tx];
  __syncthreads();
#pragma unroll
  for (int i = 0; i < 32; i += 8)
    dst[(size_t)(n0g + ty + i) * 2048 + k0 + tx] = f2bf(t[tx][ty + i]);
}

__global__ void transpose_w(const float* __restrict__ src, u16* __restrict__ dst, int N) {
  __shared__ float t[32][33];
  const int k0 = blockIdx.y * 32;
  const int n0 = blockIdx.x * 32;
  const int tx = threadIdx.x, ty = threadIdx.y;
#pragma unroll
  for (int i = 0; i < 32; i += 8)
    t[ty + i][tx] = src[(size_t)(k0 + ty + i) * N + n0 + tx];
  __syncthreads();
#pragma unroll
  for (int i = 0; i < 32; i += 8)
    dst[(size_t)(n0 + ty + i) * 2048 + k0 + tx] = f2bf(t[tx][ty + i]);
}

// cos/sin tables [ROWS][32] f32 (d < 32 only; d+32 shares values).
__global__ void cossin_k(const int* __restrict__ pos,
                         float* __restrict__ cosb, float* __restrict__ sinb) {
  int t = blockIdx.x * 256 + threadIdx.x;   // row*32 + d
  int row = t >> 5, d = t & 31;
  int sec = (d < 16) ? 0 : 1;
  float p = (float)pos[sec * ROWS + row];
  float inv_freq = powf(1.0e6f, -(float)d * (1.0f / 32.0f));
  float fr = p * inv_freq;
  float s, c;
  sincosf(fr, &s, &c);
  cosb[t] = c;
  sinb[t] = s;
}

// ---------------- BK=64 8-phase pipelined GEMM (T1+T2+T3+T4+T5) ----------------
// MODE 0: 256x256 tile, grid 16x12=192 blocks, fused bias+mRoPE QKV epilogue.
// MODE 1: 128x256 tile, grid 32x8 =256 blocks (exact fill), plain f32 store.
// 8 waves (2M x 4N); per-wave MF m-frags x 4 n-frags. Per K-tile: MF/2 phases
// of 16 MFMA each; A(kt+1) staged in phase 0, B(kt+2) staged in later phases;
// single counted vmcnt(4) at last phase (0 only at tail).
// LDS chunk swizzle: chunk ^= (row&7); global source pre-swizzled (rule 21).
// XCD-chunked bijective block swizzle (T1).

#define BAR() { __builtin_amdgcn_s_barrier(); __builtin_amdgcn_sched_barrier(0); }

#define STG(G, L, RB, h, kt) { \
    const u16* g_ = (G) + (size_t)((RB) + (h) * 128 + srow) * 2048 + (kt) * 64 + sc8; \
    gload16(g_,             (L) + (h) * 8192 + sldo);       \
    gload16(g_ + 8 * 2048,  (L) + (h) * 8192 + sldo + 512); }

#define LDAF(mm) \
    af[0][0] = *reinterpret_cast<const bf16x8_t*>(Asp + rowxA + (mm) * 1024 + cof0); \
    af[0][1] = *reinterpret_cast<const bf16x8_t*>(Asp + rowxA + (mm) * 1024 + cof1); \
    af[1][0] = *reinterpret_cast<const bf16x8_t*>(Asp + rowxA + (mm) * 1024 + 1024 + cof0); \
    af[1][1] = *reinterpret_cast<const bf16x8_t*>(Asp + rowxA + (mm) * 1024 + 1024 + cof1);

#define MFMA8(mb) \
    _Pragma("unroll") \
    for (int n = 0; n < 4; ++n) { \
      acc[(mb)][n]     = __builtin_amdgcn_mfma_f32_16x16x32_bf16(af[0][0], bfr[n][0], acc[(mb)][n], 0, 0, 0); \
      acc[(mb)][n]     = __builtin_amdgcn_mfma_f32_16x16x32_bf16(af[0][1], bfr[n][1], acc[(mb)][n], 0, 0, 0); \
      acc[(mb) + 1][n] = __builtin_amdgcn_mfma_f32_16x16x32_bf16(af[1][0], bfr[n][0], acc[(mb) + 1][n], 0, 0, 0); \
      acc[(mb) + 1][n] = __builtin_amdgcn_mfma_f32_16x16x32_bf16(af[1][1], bfr[n][1], acc[(mb) + 1][n], 0, 0, 0); \
    }

template <int MODE>
__global__ __launch_bounds__(512, 2) void gemm256(
    const u16* __restrict__ A, const u16* __restrict__ Bt,
    const float* __restrict__ bq, const float* __restrict__ bk, const float* __restrict__ bv,
    const float* __restrict__ cosb, const float* __restrict__ sinb,
    u16* __restrict__ Qb, u16* __restrict__ Kb, u16* __restrict__ Vtmp,
    float* __restrict__ Cout, int Nout) {
  constexpr int BMx = (MODE == 0) ? 256 : 128;   // M tile
  constexpr int MF  = BMx / 32;                  // per-wave m-frags (8 or 4)

  // bijective XCD-chunked swizzle (8 XCDs, round-robin dispatch assumption)
  const int lin = blockIdx.y * gridDim.x + blockIdx.x;
  int bx, by;
  if constexpr (MODE == 0) {          // 192 blocks: XCD owns 2 A-panels (2MB L2)
    int c = lin & 7, t = lin >> 3;    // t in 0..23
    bx = c * 2 + (t >= 12 ? 1 : 0);
    by = (t >= 12) ? t - 12 : t;
  } else {                            // 256 blocks: XCD owns 1 B-panel (1MB L2)
    int c = lin & 7, t = lin >> 3;    // t in 0..31
    bx = t; by = c;
  }
  const int m0 = bx * BMx;
  const int n0 = by * 256;

  __shared__ __align__(16) u16 As[2][BMx * 64];
  __shared__ __align__(16) u16 Bs[2][16384];
  const int tid  = threadIdx.x;
  const int lane = tid & 63;
  const int wv   = tid >> 6;        // 0..7
  const int wr   = wv >> 2;         // 0..1  (M half)
  const int wc   = wv & 3;          // 0..3  (N quarter)
  const int ln   = lane & 15;
  const int quad = lane >> 4;

  // staging geometry: per half-tile (128 rows x 64 cols = 16KB), wave slice is
  // 16 rows; each gload covers 8 rows. LDS dest linear; source inverse-swizzled.
  const int srow = wv * 16 + (lane >> 3);            // row within half (2nd gload +8)
  const int sc8  = ((lane & 7) ^ (lane >> 3)) * 8;   // pre-swizzled k-chunk (u16)
  const int sldo = wv * 1024;                        // u16 offset of wave slice

  // ds_read geometry: row r, chunk c -> u16 off r*64 + (c ^ (r&7))*8; r&7 == ln&7.
  const int rowxA = (wr * (BMx / 2) + ln) * 64;
  const int rowxB = (wc * 64       + ln) * 64;
  const int cof0  = ((quad    ) ^ (ln & 7)) * 8;     // kk=0 chunk = quad
  const int cof1  = ((quad ^ 4) ^ (ln & 7)) * 8;     // kk=1 chunk = 4+quad

  f32x4_t acc[MF][4];
#pragma unroll
  for (int i = 0; i < MF; i++)
#pragma unroll
    for (int j = 0; j < 4; j++)
      acc[i][j] = (f32x4_t){0.f, 0.f, 0.f, 0.f};

  // prologue: A(0), B(0), B(1). vmcnt(4) -> A(0),B(0) landed, B(1) in flight.
  STG(A, As[0], m0, 0, 0);
  if constexpr (MODE == 0) { STG(A, As[0], m0, 1, 0); }
  STG(Bt, Bs[0], n0, 0, 0); STG(Bt, Bs[0], n0, 1, 0);
  STG(Bt, Bs[1], n0, 0, 1); STG(Bt, Bs[1], n0, 1, 1);
  asm volatile("s_waitcnt vmcnt(4)" ::: "memory");
  BAR();

  for (int kt = 0; kt < 32; ++kt) {
    const int par = kt & 1;
    const u16* Asp = As[par];
    const u16* Bsp = Bs[par];
    u16* Asn = As[par ^ 1];
    u16* Bsn = Bs[par];               // B(kt+2) has same parity as B(kt)
    bf16x8_t bfr[4][2], af[2][2];

    if constexpr (MODE == 0) {
      // ---------- phase 0: all B frags + A(m0,m1); stage A(kt+1) ----------
#pragma unroll
      for (int n = 0; n < 4; ++n) {
        bfr[n][0] = *reinterpret_cast<const bf16x8_t*>(Bsp + rowxB + n * 1024 + cof0);
        bfr[n][1] = *reinterpret_cast<const bf16x8_t*>(Bsp + rowxB + n * 1024 + cof1);
      }
      LDAF(0);
      if (kt + 1 < 32) { STG(A, Asn, m0, 0, kt + 1); STG(A, Asn, m0, 1, kt + 1); }
      BAR();
      __builtin_amdgcn_s_setprio(1);
      MFMA8(0);
      __builtin_amdgcn_s_setprio(0);
      BAR();

      // ---------- phase 1: A(m2,m3); stage B half0 (kt+2) ----------
      LDAF(2);
      if (kt + 2 < 32) { STG(Bt, Bsn, n0, 0, kt + 2); }
      BAR();
      __builtin_amdgcn_s_setprio(1);
      MFMA8(2);
      __builtin_amdgcn_s_setprio(0);
      BAR();

      // ---------- phase 2: A(m4,m5); stage B half1 (kt+2) ----------
      LDAF(4);
      if (kt + 2 < 32) { STG(Bt, Bsn, n0, 1, kt + 2); }
      BAR();
      __builtin_amdgcn_s_setprio(1);
      MFMA8(4);
      __builtin_amdgcn_s_setprio(0);
      BAR();

      // ---------- phase 3: A(m6,m7); counted vmcnt drains next tile ----------
      LDAF(6);
      BAR();
      __builtin_amdgcn_s_setprio(1);
      MFMA8(6);
      __builtin_amdgcn_s_setprio(0);
      if (kt + 2 < 32) { asm volatile("s_waitcnt vmcnt(4)" ::: "memory"); }
      else             { asm volatile("s_waitcnt vmcnt(0)" ::: "memory"); }
      BAR();
    } else {
      // ---------- phase 0: all B frags + A(m0,m1); stage A(kt+1) ----------
#pragma unroll
      for (int n = 0; n < 4; ++n) {
        bfr[n][0] = *reinterpret_cast<const bf16x8_t*>(Bsp + rowxB + n * 1024 + cof0);
        bfr[n][1] = *reinterpret_cast<const bf16x8_t*>(Bsp + rowxB + n * 1024 + cof1);
      }
      LDAF(0);
      if (kt + 1 < 32) { STG(A, Asn, m0, 0, kt + 1); }
      BAR();
      __builtin_amdgcn_s_setprio(1);
      MFMA8(0);
      __builtin_amdgcn_s_setprio(0);
      BAR();

      // ---------- phase 1: A(m2,m3); stage B both halves (kt+2); vmcnt ----------
      LDAF(2);
      if (kt + 2 < 32) { STG(Bt, Bsn, n0, 0, kt + 2); STG(Bt, Bsn, n0, 1, kt + 2); }
      BAR();
      __builtin_amdgcn_s_setprio(1);
      MFMA8(2);
      __builtin_amdgcn_s_setprio(0);
      if (kt + 2 < 32) { asm volatile("s_waitcnt vmcnt(4)" ::: "memory"); }
      else             { asm volatile("s_waitcnt vmcnt(0)" ::: "memory"); }
      BAR();
    }
  }

  if constexpr (MODE == 0) {
    const int colbase = n0 + wc * 64;   // multiple of 64 -> one head per wave
    if (n0 < 2048) {
      const int hq = colbase >> 6;
#pragma unroll
      for (int i = 0; i < MF; i++) {
        int rw0 = m0 + wr * (BMx / 2) + i * 16 + quad * 4;
#pragma unroll
        for (int j = 0; j < 2; j++) {
          int d = j * 16 + ln;     // < 32
          float b0 = bq[colbase + d];
          float b1 = bq[colbase + d + 32];
#pragma unroll
          for (int r = 0; r < 4; r++) {
            int row = rw0 + r;
            float c  = cosb[row * 32 + d];
            float sn = sinb[row * 32 + d];
            float v0 = acc[i][j][r]     + b0;
            float v1 = acc[i][j + 2][r] + b1;
            int bb = row >> 11, s = row & (S_ - 1);
            size_t base = ((size_t)(bb * NH_ + hq) * S_ + s) * HD_;
            Qb[base + d]      = f2bf((v0 * c - v1 * sn) * 0.125f);
            Qb[base + d + 32] = f2bf((v1 * c + v0 * sn) * 0.125f);
          }
        }
      }
    } else if (n0 < 2560) {
      const int kh = (colbase - 2048) >> 6;
#pragma unroll
      for (int i = 0; i < MF; i++) {
        int rw0 = m0 + wr * (BMx / 2) + i * 16 + quad * 4;
#pragma unroll
        for (int j = 0; j < 2; j++) {
          int d = j * 16 + ln;
          float b0 = bk[(colbase - 2048) + d];
          float b1 = bk[(colbase - 2048) + d + 32];
#pragma unroll
          for (int r = 0; r < 4; r++) {
            int row = rw0 + r;
            float c  = cosb[row * 32 + d];
            float sn = sinb[row * 32 + d];
            float v0 = acc[i][j][r]     + b0;
            float v1 = acc[i][j + 2][r] + b1;
            int bb = row >> 11, s = row & (S_ - 1);
            size_t base = ((size_t)(bb * NKV_ + kh) * S_ + s) * HD_;
            Kb[base + d]      = f2bf(v0 * c - v1 * sn);
            Kb[base + d + 32] = f2bf(v1 * c + v0 * sn);
          }
        }
      }
    } else {
#pragma unroll
      for (int i = 0; i < MF; i++) {
        int rw0 = m0 + wr * (BMx / 2) + i * 16 + quad * 4;
#pragma unroll
        for (int j = 0; j < 4; j++) {
          int cv = colbase - 2560 + j * 16 + ln;
          float bvv = bv[cv];
#pragma unroll
          for (int r = 0; r < 4; r++)
            Vtmp[(size_t)(rw0 + r) * 512 + cv] = f2bf(acc[i][j][r] + bvv);
        }
      }
    }
  } else {
#pragma unroll
    for (int i = 0; i < MF; i++) {
      int row = m0 + wr * (BMx / 2) + i * 16 + quad * 4;
#pragma unroll
      for (int j = 0; j < 4; j++) {
        int col = n0 + wc * 64 + j * 16 + ln;
        float* cp = Cout + (size_t)row * Nout + col;
#pragma unroll
        for (int r = 0; r < 4; r++)
          cp[(size_t)r * Nout] = acc[i][j][r];
      }
    }
  }
}

// V^T with kv-permuted columns from bf16 Vtmp [4096][512].
__global__ void prep_v(const u16* __restrict__ Vtmp, u16* __restrict__ Vt) {
  __shared__ u16 tile[64][65];
  const int sb  = blockIdx.x * 64;
  const int bk  = blockIdx.y;
  const int b   = bk >> 3, kvh = bk & 7;
  const int tx  = threadIdx.x & 63;
  const int ty  = threadIdx.x >> 6;   // 0..3
  const u16* src = Vtmp + (size_t)(b * 2048 + sb) * 512 + kvh * 64;
#pragma unroll
  for (int i = ty; i < 64; i += 4)
    tile[i][tx] = src[(size_t)i * 512 + tx];
  __syncthreads();
  const int sp = sb + (tx & 15) * 4 + (tx >> 4);   // permuted col
  u16* dst = Vt + (size_t)(b * NKV_ + kvh) * HD_ * (size_t)S_;
#pragma unroll
  for (int j = ty; j < 64; j += 4)
    dst[(size_t)j * S_ + sp] = tile[tx][j];
}

// ---------------- causal GQA flash attention (v6: Br=32, LDS-staged K/V) ----------------
__global__ __launch_bounds__(256, 2) void flash_attn(
    const u16* __restrict__ Qb, const u16* __restrict__ Kb, const u16* __restrict__ Vt,
    u16* __restrict__ Og) {
  const int u    = blockIdx.x;        // 0..31
  const int bk   = blockIdx.y;
  const int b    = bk >> 3;
  const int kvh  = bk & 7;
  const int tid  = threadIdx.x;
  const int wv   = tid >> 6;
  const int h    = kvh * 4 + wv;
  const int lane = tid & 63;
  const int ln   = lane & 15;
  const int quad = lane >> 4;

  __shared__ __align__(16) u16 Kl[2][64 * 64];
  __shared__ __align__(16) u16 Vl[2][64 * 64];
  __shared__ __align__(16) u16 Plds[4][2][16][72];

  const u16* Qbase = Qb + ((size_t)(b * NH_ + h) * S_) * HD_;
  const u16* Kbase = Kb + ((size_t)(b * NKV_ + kvh) * S_) * HD_;
  const u16* Vbase = Vt + ((size_t)(b * NKV_ + kvh) * HD_) * S_;

  const int j0 = wv * 2, j1 = wv * 2 + 1;
  const int p0 = j0 * 64 + lane,  p1 = j1 * 64 + lane;
  const int r0 = p0 >> 3,  c0 = (p0 & 7) ^ (r0 & 7);
  const int r1 = p1 >> 3,  c1 = (p1 & 7) ^ (r1 & 7);

  const int sw  = ln & 7;
  const int ck0 = quad ^ sw;
  const int ck1 = ck0 ^ 4;

  const int tlist[2] = {u, 63 - u};

  for (int ti = 0; ti < 2; ++ti) {
    const int t = tlist[ti];
    const int qrow0 = t * 32;

    bf16x8_t qf[2][2];
#pragma unroll
    for (int mt = 0; mt < 2; mt++) {
      qf[mt][0] = *reinterpret_cast<const bf16x8_t*>(
          Qbase + (size_t)(qrow0 + mt * 16 + ln) * HD_ + quad * 8);
      qf[mt][1] = *reinterpret_cast<const bf16x8_t*>(
          Qbase + (size_t)(qrow0 + mt * 16 + ln) * HD_ + 32 + quad * 8);
    }

    f32x4_t O[2][4];
#pragma unroll
    for (int mt = 0; mt < 2; mt++)
#pragma unroll
      for (int dt = 0; dt < 4; dt++)
        O[mt][dt] = (f32x4_t){0.f, 0.f, 0.f, 0.f};
    float l[2][4];
#pragma unroll
    for (int mt = 0; mt < 2; mt++)
#pragma unroll
      for (int r = 0; r < 4; r++) l[mt][r] = 0.f;

    const int nsteps = t / 2 + 1;

    __syncthreads();   // all waves done reading buffers (prev tile)
    gload16(Kbase + (size_t)r0 * HD_ + c0 * 8, &Kl[0][j0 * 512]);
    gload16(Kbase + (size_t)r1 * HD_ + c1 * 8, &Kl[0][j1 * 512]);
    gload16(Vbase + (size_t)r0 * S_ + c0 * 8,  &Vl[0][j0 * 512]);
    gload16(Vbase + (size_t)r1 * S_ + c1 * 8,  &Vl[0][j1 * 512]);

    for (int step = 0; step < nsteps; ++step) {
      const int cur = step & 1;
      const int kv0 = step * 64;
      __syncthreads();   // drains vmcnt -> buf[cur] ready; buf[cur^1] readers done

      if (step + 1 < nsteps) {
        const int nb  = cur ^ 1;
        const int nkv = kv0 + 64;
        gload16(Kbase + (size_t)(nkv + r0) * HD_ + c0 * 8, &Kl[nb][j0 * 512]);
        gload16(Kbase + (size_t)(nkv + r1) * HD_ + c1 * 8, &Kl[nb][j1 * 512]);
        gload16(Vbase + (size_t)r0 * S_ + nkv + c0 * 8,    &Vl[nb][j0 * 512]);
        gload16(Vbase + (size_t)r1 * S_ + nkv + c1 * 8,    &Vl[nb][j1 * 512]);
      }

      const u16* Kc = Kl[cur];
      const u16* Vc = Vl[cur];

      bf16x8_t kf0[4], kf1[4];
#pragma unroll
      for (int kt = 0; kt < 4; kt++) {
        const u16* rp = Kc + (kt * 16 + ln) * 64;
        kf0[kt] = *reinterpret_cast<const bf16x8_t*>(rp + ck0 * 8);
        kf1[kt] = *reinterpret_cast<const bf16x8_t*>(rp + ck1 * 8);
      }
      f32x4_t s[2][4];
#pragma unroll
      for (int mt = 0; mt < 2; mt++)
#pragma unroll
        for (int kt = 0; kt < 4; kt++) {
          f32x4_t acc = (f32x4_t){0.f, 0.f, 0.f, 0.f};
          acc = __builtin_amdgcn_mfma_f32_16x16x32_bf16(qf[mt][0], kf0[kt], acc, 0, 0, 0);
          acc = __builtin_amdgcn_mfma_f32_16x16x32_bf16(qf[mt][1], kf1[kt], acc, 0, 0, 0);
          s[mt][kt] = acc;
        }

      bf16x8_t vf0[4], vf1[4];
#pragma unroll
      for (int dt = 0; dt < 4; dt++) {
        const u16* rp = Vc + (dt * 16 + ln) * 64;
        vf0[dt] = *reinterpret_cast<const bf16x8_t*>(rp + ck0 * 8);
        vf1[dt] = *reinterpret_cast<const bf16x8_t*>(rp + ck1 * 8);
      }

      if (kv0 + 63 > qrow0) {
#pragma unroll
        for (int mt = 0; mt < 2; mt++)
#pragma unroll
          for (int kt = 0; kt < 4; kt++)
#pragma unroll
            for (int r = 0; r < 4; r++) {
              int rowg = qrow0 + mt * 16 + quad * 4 + r;
              if (kv0 + kt * 16 + ln > rowg) s[mt][kt][r] = -1e30f;
            }
      }

#pragma unroll
      for (int mt = 0; mt < 2; mt++)
#pragma unroll
        for (int r = 0; r < 4; r++) {
          float p0f = __expf(s[mt][0][r] - MEXP);
          float p1f = __expf(s[mt][1][r] - MEXP);
          float p2f = __expf(s[mt][2][r] - MEXP);
          float p3f = __expf(s[mt][3][r] - MEXP);
          l[mt][r] += (p0f + p1f) + (p2f + p3f);
          ushort4 pk;   // truncation pack (bias cancels in O/l)
          pk.x = (u16)(__float_as_uint(p0f) >> 16);
          pk.y = (u16)(__float_as_uint(p1f) >> 16);
          pk.z = (u16)(__float_as_uint(p2f) >> 16);
          pk.w = (u16)(__float_as_uint(p3f) >> 16);
          *reinterpret_cast<ushort4*>(&Plds[wv][mt][quad * 4 + r][ln * 4]) = pk;
        }

#pragma unroll
      for (int mt = 0; mt < 2; mt++) {
        bf16x8_t pf0 = *reinterpret_cast<const bf16x8_t*>(&Plds[wv][mt][ln][quad * 8]);
        bf16x8_t pf1 = *reinterpret_cast<const bf16x8_t*>(&Plds[wv][mt][ln][32 + quad * 8]);
#pragma unroll
        for (int dt = 0; dt < 4; dt++) {
          O[mt][dt] = __builtin_amdgcn_mfma_f32_16x16x32_bf16(pf0, vf0[dt], O[mt][dt], 0, 0, 0);
          O[mt][dt] = __builtin_amdgcn_mfma_f32_16x16x32_bf16(pf1, vf1[dt], O[mt][dt], 0, 0, 0);
        }
      }
    }

#pragma unroll
    for (int mt = 0; mt < 2; mt++)
#pragma unroll
      for (int r = 0; r < 4; r++) {
        float lv = l[mt][r];
        lv += __shfl_xor(lv, 1);
        lv += __shfl_xor(lv, 2);
        lv += __shfl_xor(lv, 4);
        lv += __shfl_xor(lv, 8);
        float inv = 1.0f / lv;
        int srow = qrow0 + mt * 16 + quad * 4 + r;
        size_t base = ((size_t)b * S_ + srow) * (size_t)(NH_ * HD_) + h * HD_;
#pragma unroll
        for (int dt = 0; dt < 4; dt++)
          Og[base + dt * 16 + ln] = f2bf(O[mt][dt][r] * inv);
      }
  }
}

// ---------------- launch ----------------

extern "C" void kernel_launch(void* const* d_in, const int* in_sizes, int n_in,
                              void* d_out, int out_size, void* d_ws, size_t ws_size,
                              hipStream_t stream) {
  const float* x  = (const float*)d_in[0];
  const int*   pos = (const int*)d_in[1];
  const float* Wq = (const float*)d_in[2];
  const float* bq = (const float*)d_in[3];
  const float* Wk = (const float*)d_in[4];
  const float* bk = (const float*)d_in[5];
  const float* Wv = (const float*)d_in[6];
  const float* bv = (const float*)d_in[7];
  const float* Wo = (const float*)d_in[8];
  float* out = (float*)d_out;

  char* ws = (char*)d_ws;
  u16*   xb    = (u16*)(ws);                     // [4096][2048] bf16   16.8MB
  u16*   Wqkvt = (u16*)(ws + 16777216);          // [3072][2048] bf16   12.6MB
  u16*   Wot   = (u16*)(ws + 29360128);          // [2048][2048] bf16    8.4MB
  float* cosb  = (float*)(ws + 37748736);        // [4096][32] f32
  float* sinb  = (float*)(ws + 38797312);        // [4096][32] f32
  u16*   Qb    = (u16*)(ws + 39845888);          // [B][NH][S][HD]      16.8MB
  u16*   Kb    = (u16*)(ws + 56623104);          // [B][NKV][S][HD]      4.2MB
  u16*   Vtmp  = (u16*)(ws + 60817408);          // [4096][512] bf16     4.2MB
  u16*   Vt    = (u16*)(ws + 65011712);          // [B][NKV][HD][S]      4.2MB (kv-permuted)
  u16*   Og    = (u16*)(ws + 69206016);          // [4096][2048] bf16   16.8MB

  cvt_bf16<<<ROWS * H_ / 4 / 256, 256, 0, stream>>>(x, xb, ROWS * H_ / 4);
  transpose_wqkv<<<dim3(96, 64), dim3(32, 8), 0, stream>>>(Wq, Wk, Wv, Wqkvt);
  transpose_w<<<dim3(64, 64), dim3(32, 8), 0, stream>>>(Wo, Wot, 2048);
  cossin_k<<<ROWS * 32 / 256, 256, 0, stream>>>(pos, cosb, sinb);

  gemm256<0><<<dim3(16, 12), 512, 0, stream>>>(xb, Wqkvt, bq, bk, bv, cosb, sinb,
                                               Qb, Kb, Vtmp, nullptr, 0);

  prep_v<<<dim3(32, 16), 256, 0, stream>>>(Vtmp, Vt);

  flash_attn<<<dim3(32, 16), 256, 0, stream>>>(Qb, Kb, Vt, Og);

  gemm256<1><<<dim3(32, 8), 512, 0, stream>>>(Og, Wot, nullptr, nullptr, nullptr,
                                              nullptr, nullptr, nullptr, nullptr, nullptr,
                                              out, 2048);
}

// Round 3
// 307.402 us; speedup vs baseline: 1.0668x; 1.0129x over previous
//
#include <hip/hip_runtime.h>

#define B_   2
#define S_   2048
#define H_   2048
#define NH_  32
#define NKV_ 8
#define HD_  64
#define ROWS (B_*S_)   // 4096
#define MEXP 20.0f

typedef unsigned short u16;
typedef __bf16 bf16x8_t __attribute__((ext_vector_type(8)));
typedef float  f32x4_t  __attribute__((ext_vector_type(4)));

__device__ __forceinline__ u16 f2bf(float f) {
  union { float f; unsigned u; } v; v.f = f;
  unsigned u = v.u;
  u += 0x7FFFu + ((u >> 16) & 1u);
  return (u16)(u >> 16);
}

// async global->LDS, 16B per lane. LDS dest = wave-uniform base + lane*16.
__device__ __forceinline__ void gload16(const u16* g, u16* l) {
  __builtin_amdgcn_global_load_lds((const __attribute__((address_space(1))) void*)g,
                                   (__attribute__((address_space(3))) void*)l, 16, 0, 0);
}

// ---------------- elementwise converts / prep ----------------

__global__ void cvt_bf16(const float* __restrict__ src, u16* __restrict__ dst, int n4) {
  int i = blockIdx.x * 256 + threadIdx.x;
  if (i >= n4) return;
  float4 v = reinterpret_cast<const float4*>(src)[i];
  ushort4 o;
  o.x = f2bf(v.x); o.y = f2bf(v.y); o.z = f2bf(v.z); o.w = f2bf(v.w);
  reinterpret_cast<ushort4*>(dst)[i] = o;
}

// merged transpose of Wq|Wk|Wv -> Wqkvt [3072][2048] bf16. grid (96,64),(32,8)
__global__ void transpose_wqkv(const float* __restrict__ Wq, const float* __restrict__ Wk,
                               const float* __restrict__ Wv, u16* __restrict__ dst) {
  __shared__ float t[32][33];
  const int k0  = blockIdx.y * 32;
  const int n0g = blockIdx.x * 32;
  const float* src; int N, n0;
  if (n0g < 2048)      { src = Wq; N = 2048; n0 = n0g; }
  else if (n0g < 2560) { src = Wk; N = 512;  n0 = n0g - 2048; }
  else                 { src = Wv; N = 512;  n0 = n0g - 2560; }
  const int tx = threadIdx.x, ty = threadIdx.y;
#pragma unroll
  for (int i = 0; i < 32; i += 8)
    t[ty + i][tx] = src[(size_t)(k0 + ty + i) * N + n0 + tx];
  __syncthreads();
#pragma unroll
  for (int i = 0; i < 32; i += 8)
    dst[(size_t)(n0g + ty + i) * 2048 + k0 + tx] = f2bf(t[tx][ty + i]);
}

__global__ void transpose_w(const float* __restrict__ src, u16* __restrict__ dst, int N) {
  __shared__ float t[32][33];
  const int k0 = blockIdx.y * 32;
  const int n0 = blockIdx.x * 32;
  const int tx = threadIdx.x, ty = threadIdx.y;
#pragma unroll
  for (int i = 0; i < 32; i += 8)
    t[ty + i][tx] = src[(size_t)(k0 + ty + i) * N + n0 + tx];
  __syncthreads();
#pragma unroll
  for (int i = 0; i < 32; i += 8)
    dst[(size_t)(n0 + ty + i) * 2048 + k0 + tx] = f2bf(t[tx][ty + i]);
}

// cos/sin tables [ROWS][32] f32 (d < 32 only; d+32 shares values).
__global__ void cossin_k(const int* __restrict__ pos,
                         float* __restrict__ cosb, float* __restrict__ sinb) {
  int t = blockIdx.x * 256 + threadIdx.x;   // row*32 + d
  int row = t >> 5, d = t & 31;
  int sec = (d < 16) ? 0 : 1;
  float p = (float)pos[sec * ROWS + row];
  float inv_freq = powf(1.0e6f, -(float)d * (1.0f / 32.0f));
  float fr = p * inv_freq;
  float s, c;
  sincosf(fr, &s, &c);
  cosb[t] = c;
  sinb[t] = s;
}

// ---------------- BK=64 8-phase pipelined GEMM (T2+T3+T4+T5) ----------------
// MODE 0: 256x256 tile, grid 16x12=192 blocks, fused bias+mRoPE QKV epilogue.
// MODE 1: 128x256 tile, grid 32x8 =256 blocks (exact fill), plain f32 store.
// Natural block order (R2's XCD remap measured -16% on MODE 0; reverted).
// 8 waves (2M x 4N); per K-tile: MF/2 phases of 16 MFMA each; A(kt+1) staged
// in phase 0, B(kt+2) in later phases; counted vmcnt(4) at last phase.
// LDS chunk swizzle: chunk ^= (row&7); global source pre-swizzled (rule 21).

#define BAR() { __builtin_amdgcn_s_barrier(); __builtin_amdgcn_sched_barrier(0); }

#define STG(G, L, RB, h, kt) { \
    const u16* g_ = (G) + (size_t)((RB) + (h) * 128 + srow) * 2048 + (kt) * 64 + sc8; \
    gload16(g_,             (L) + (h) * 8192 + sldo);       \
    gload16(g_ + 8 * 2048,  (L) + (h) * 8192 + sldo + 512); }

#define LDAF(mm) \
    af[0][0] = *reinterpret_cast<const bf16x8_t*>(Asp + rowxA + (mm) * 1024 + cof0); \
    af[0][1] = *reinterpret_cast<const bf16x8_t*>(Asp + rowxA + (mm) * 1024 + cof1); \
    af[1][0] = *reinterpret_cast<const bf16x8_t*>(Asp + rowxA + (mm) * 1024 + 1024 + cof0); \
    af[1][1] = *reinterpret_cast<const bf16x8_t*>(Asp + rowxA + (mm) * 1024 + 1024 + cof1);

#define MFMA8(mb) \
    _Pragma("unroll") \
    for (int n = 0; n < 4; ++n) { \
      acc[(mb)][n]     = __builtin_amdgcn_mfma_f32_16x16x32_bf16(af[0][0], bfr[n][0], acc[(mb)][n], 0, 0, 0); \
      acc[(mb)][n]     = __builtin_amdgcn_mfma_f32_16x16x32_bf16(af[0][1], bfr[n][1], acc[(mb)][n], 0, 0, 0); \
      acc[(mb) + 1][n] = __builtin_amdgcn_mfma_f32_16x16x32_bf16(af[1][0], bfr[n][0], acc[(mb) + 1][n], 0, 0, 0); \
      acc[(mb) + 1][n] = __builtin_amdgcn_mfma_f32_16x16x32_bf16(af[1][1], bfr[n][1], acc[(mb) + 1][n], 0, 0, 0); \
    }

template <int MODE>
__global__ __launch_bounds__(512, 2) void gemm256(
    const u16* __restrict__ A, const u16* __restrict__ Bt,
    const float* __restrict__ bq, const float* __restrict__ bk, const float* __restrict__ bv,
    const float* __restrict__ cosb, const float* __restrict__ sinb,
    u16* __restrict__ Qb, u16* __restrict__ Kb, u16* __restrict__ Vtmp,
    float* __restrict__ Cout, int Nout) {
  constexpr int BMx = (MODE == 0) ? 256 : 128;   // M tile
  constexpr int MF  = BMx / 32;                  // per-wave m-frags (8 or 4)

  const int m0 = blockIdx.x * BMx;
  const int n0 = blockIdx.y * 256;

  __shared__ __align__(16) u16 As[2][BMx * 64];
  __shared__ __align__(16) u16 Bs[2][16384];
  const int tid  = threadIdx.x;
  const int lane = tid & 63;
  const int wv   = tid >> 6;        // 0..7
  const int wr   = wv >> 2;         // 0..1  (M half)
  const int wc   = wv & 3;          // 0..3  (N quarter)
  const int ln   = lane & 15;
  const int quad = lane >> 4;

  // staging geometry: per half-tile (128 rows x 64 cols = 16KB), wave slice is
  // 16 rows; each gload covers 8 rows. LDS dest linear; source inverse-swizzled.
  const int srow = wv * 16 + (lane >> 3);            // row within half (2nd gload +8)
  const int sc8  = ((lane & 7) ^ (lane >> 3)) * 8;   // pre-swizzled k-chunk (u16)
  const int sldo = wv * 1024;                        // u16 offset of wave slice

  // ds_read geometry: row r, chunk c -> u16 off r*64 + (c ^ (r&7))*8; r&7 == ln&7.
  const int rowxA = (wr * (BMx / 2) + ln) * 64;
  const int rowxB = (wc * 64       + ln) * 64;
  const int cof0  = ((quad    ) ^ (ln & 7)) * 8;     // kk=0 chunk = quad
  const int cof1  = ((quad ^ 4) ^ (ln & 7)) * 8;     // kk=1 chunk = 4+quad

  f32x4_t acc[MF][4];
#pragma unroll
  for (int i = 0; i < MF; i++)
#pragma unroll
    for (int j = 0; j < 4; j++)
      acc[i][j] = (f32x4_t){0.f, 0.f, 0.f, 0.f};

  // prologue: A(0), B(0), B(1). vmcnt(4) -> A(0),B(0) landed, B(1) in flight.
  STG(A, As[0], m0, 0, 0);
  if constexpr (MODE == 0) { STG(A, As[0], m0, 1, 0); }
  STG(Bt, Bs[0], n0, 0, 0); STG(Bt, Bs[0], n0, 1, 0);
  STG(Bt, Bs[1], n0, 0, 1); STG(Bt, Bs[1], n0, 1, 1);
  asm volatile("s_waitcnt vmcnt(4)" ::: "memory");
  BAR();

  for (int kt = 0; kt < 32; ++kt) {
    const int par = kt & 1;
    const u16* Asp = As[par];
    const u16* Bsp = Bs[par];
    u16* Asn = As[par ^ 1];
    u16* Bsn = Bs[par];               // B(kt+2) has same parity as B(kt)
    bf16x8_t bfr[4][2], af[2][2];

    if constexpr (MODE == 0) {
      // ---------- phase 0: all B frags + A(m0,m1); stage A(kt+1) ----------
#pragma unroll
      for (int n = 0; n < 4; ++n) {
        bfr[n][0] = *reinterpret_cast<const bf16x8_t*>(Bsp + rowxB + n * 1024 + cof0);
        bfr[n][1] = *reinterpret_cast<const bf16x8_t*>(Bsp + rowxB + n * 1024 + cof1);
      }
      LDAF(0);
      if (kt + 1 < 32) { STG(A, Asn, m0, 0, kt + 1); STG(A, Asn, m0, 1, kt + 1); }
      BAR();
      __builtin_amdgcn_s_setprio(1);
      MFMA8(0);
      __builtin_amdgcn_s_setprio(0);
      BAR();

      // ---------- phase 1: A(m2,m3); stage B half0 (kt+2) ----------
      LDAF(2);
      if (kt + 2 < 32) { STG(Bt, Bsn, n0, 0, kt + 2); }
      BAR();
      __builtin_amdgcn_s_setprio(1);
      MFMA8(2);
      __builtin_amdgcn_s_setprio(0);
      BAR();

      // ---------- phase 2: A(m4,m5); stage B half1 (kt+2) ----------
      LDAF(4);
      if (kt + 2 < 32) { STG(Bt, Bsn, n0, 1, kt + 2); }
      BAR();
      __builtin_amdgcn_s_setprio(1);
      MFMA8(4);
      __builtin_amdgcn_s_setprio(0);
      BAR();

      // ---------- phase 3: A(m6,m7); counted vmcnt drains next tile ----------
      LDAF(6);
      BAR();
      __builtin_amdgcn_s_setprio(1);
      MFMA8(6);
      __builtin_amdgcn_s_setprio(0);
      if (kt + 2 < 32) { asm volatile("s_waitcnt vmcnt(4)" ::: "memory"); }
      else             { asm volatile("s_waitcnt vmcnt(0)" ::: "memory"); }
      BAR();
    } else {
      // ---------- phase 0: all B frags + A(m0,m1); stage A(kt+1) ----------
#pragma unroll
      for (int n = 0; n < 4; ++n) {
        bfr[n][0] = *reinterpret_cast<const bf16x8_t*>(Bsp + rowxB + n * 1024 + cof0);
        bfr[n][1] = *reinterpret_cast<const bf16x8_t*>(Bsp + rowxB + n * 1024 + cof1);
      }
      LDAF(0);
      if (kt + 1 < 32) { STG(A, Asn, m0, 0, kt + 1); }
      BAR();
      __builtin_amdgcn_s_setprio(1);
      MFMA8(0);
      __builtin_amdgcn_s_setprio(0);
      BAR();

      // ---------- phase 1: A(m2,m3); stage B both halves (kt+2); vmcnt ----------
      LDAF(2);
      if (kt + 2 < 32) { STG(Bt, Bsn, n0, 0, kt + 2); STG(Bt, Bsn, n0, 1, kt + 2); }
      BAR();
      __builtin_amdgcn_s_setprio(1);
      MFMA8(2);
      __builtin_amdgcn_s_setprio(0);
      if (kt + 2 < 32) { asm volatile("s_waitcnt vmcnt(4)" ::: "memory"); }
      else             { asm volatile("s_waitcnt vmcnt(0)" ::: "memory"); }
      BAR();
    }
  }

  if constexpr (MODE == 0) {
    const int colbase = n0 + wc * 64;   // multiple of 64 -> one head per wave
    if (n0 < 2048) {
      const int hq = colbase >> 6;
#pragma unroll
      for (int i = 0; i < MF; i++) {
        int rw0 = m0 + wr * (BMx / 2) + i * 16 + quad * 4;
#pragma unroll
        for (int j = 0; j < 2; j++) {
          int d = j * 16 + ln;     // < 32
          float b0 = bq[colbase + d];
          float b1 = bq[colbase + d + 32];
#pragma unroll
          for (int r = 0; r < 4; r++) {
            int row = rw0 + r;
            float c  = cosb[row * 32 + d];
            float sn = sinb[row * 32 + d];
            float v0 = acc[i][j][r]     + b0;
            float v1 = acc[i][j + 2][r] + b1;
            int bb = row >> 11, s = row & (S_ - 1);
            size_t base = ((size_t)(bb * NH_ + hq) * S_ + s) * HD_;
            Qb[base + d]      = f2bf((v0 * c - v1 * sn) * 0.125f);
            Qb[base + d + 32] = f2bf((v1 * c + v0 * sn) * 0.125f);
          }
        }
      }
    } else if (n0 < 2560) {
      const int kh = (colbase - 2048) >> 6;
#pragma unroll
      for (int i = 0; i < MF; i++) {
        int rw0 = m0 + wr * (BMx / 2) + i * 16 + quad * 4;
#pragma unroll
        for (int j = 0; j < 2; j++) {
          int d = j * 16 + ln;
          float b0 = bk[(colbase - 2048) + d];
          float b1 = bk[(colbase - 2048) + d + 32];
#pragma unroll
          for (int r = 0; r < 4; r++) {
            int row = rw0 + r;
            float c  = cosb[row * 32 + d];
            float sn = sinb[row * 32 + d];
            float v0 = acc[i][j][r]     + b0;
            float v1 = acc[i][j + 2][r] + b1;
            int bb = row >> 11, s = row & (S_ - 1);
            size_t base = ((size_t)(bb * NKV_ + kh) * S_ + s) * HD_;
            Kb[base + d]      = f2bf(v0 * c - v1 * sn);
            Kb[base + d + 32] = f2bf(v1 * c + v0 * sn);
          }
        }
      }
    } else {
#pragma unroll
      for (int i = 0; i < MF; i++) {
        int rw0 = m0 + wr * (BMx / 2) + i * 16 + quad * 4;
#pragma unroll
        for (int j = 0; j < 4; j++) {
          int cv = colbase - 2560 + j * 16 + ln;
          float bvv = bv[cv];
#pragma unroll
          for (int r = 0; r < 4; r++)
            Vtmp[(size_t)(rw0 + r) * 512 + cv] = f2bf(acc[i][j][r] + bvv);
        }
      }
    }
  } else {
#pragma unroll
    for (int i = 0; i < MF; i++) {
      int row = m0 + wr * (BMx / 2) + i * 16 + quad * 4;
#pragma unroll
      for (int j = 0; j < 4; j++) {
        int col = n0 + wc * 64 + j * 16 + ln;
        float* cp = Cout + (size_t)row * Nout + col;
#pragma unroll
        for (int r = 0; r < 4; r++)
          cp[(size_t)r * Nout] = acc[i][j][r];
      }
    }
  }
}

// V^T with kv-permuted columns from bf16 Vtmp [4096][512].
__global__ void prep_v(const u16* __restrict__ Vtmp, u16* __restrict__ Vt) {
  __shared__ u16 tile[64][65];
  const int sb  = blockIdx.x * 64;
  const int bk  = blockIdx.y;
  const int b   = bk >> 3, kvh = bk & 7;
  const int tx  = threadIdx.x & 63;
  const int ty  = threadIdx.x >> 6;   // 0..3
  const u16* src = Vtmp + (size_t)(b * 2048 + sb) * 512 + kvh * 64;
#pragma unroll
  for (int i = ty; i < 64; i += 4)
    tile[i][tx] = src[(size_t)i * 512 + tx];
  __syncthreads();
  const int sp = sb + (tx & 15) * 4 + (tx >> 4);   // permuted col
  u16* dst = Vt + (size_t)(b * NKV_ + kvh) * HD_ * (size_t)S_;
#pragma unroll
  for (int j = ty; j < 64; j += 4)
    dst[(size_t)j * S_ + sp] = tile[tx][j];
}

// ---------------- causal GQA flash attention ----------------
// v7: 3-buffer K/V ring, prefetch 2 steps ahead, counted vmcnt(4) + raw
// s_barrier (T3/T4) instead of per-step __syncthreads vmcnt(0) drain.
// Safety: K/V LDS writes only via gload_lds (per-wave vmcnt, waited before
// the publishing barrier); each wave's ds_reads complete before it reaches
// the next barrier (register consumption forces lgkm waits); buffer b is
// re-staged 3 steps after its last reader passed a barrier.
__global__ __launch_bounds__(256, 2) void flash_attn(
    const u16* __restrict__ Qb, const u16* __restrict__ Kb, const u16* __restrict__ Vt,
    u16* __restrict__ Og) {
  const int u    = blockIdx.x;        // 0..31
  const int bk   = blockIdx.y;
  const int b    = bk >> 3;
  const int kvh  = bk & 7;
  const int tid  = threadIdx.x;
  const int wv   = tid >> 6;
  const int h    = kvh * 4 + wv;
  const int lane = tid & 63;
  const int ln   = lane & 15;
  const int quad = lane >> 4;

  __shared__ __align__(16) u16 Kl[3][64 * 64];
  __shared__ __align__(16) u16 Vl[3][64 * 64];
  __shared__ __align__(16) u16 Plds[4][2][16][72];

  const u16* Qbase = Qb + ((size_t)(b * NH_ + h) * S_) * HD_;
  const u16* Kbase = Kb + ((size_t)(b * NKV_ + kvh) * S_) * HD_;
  const u16* Vbase = Vt + ((size_t)(b * NKV_ + kvh) * HD_) * S_;

  const int j0 = wv * 2, j1 = wv * 2 + 1;
  const int p0 = j0 * 64 + lane,  p1 = j1 * 64 + lane;
  const int r0 = p0 >> 3,  c0 = (p0 & 7) ^ (r0 & 7);
  const int r1 = p1 >> 3,  c1 = (p1 & 7) ^ (r1 & 7);

  const int sw  = ln & 7;
  const int ck0 = quad ^ sw;
  const int ck1 = ck0 ^ 4;

  const int tlist[2] = {u, 63 - u};

  for (int ti = 0; ti < 2; ++ti) {
    const int t = tlist[ti];
    const int qrow0 = t * 32;
    const int nsteps = t / 2 + 1;

    bf16x8_t qf[2][2];
#pragma unroll
    for (int mt = 0; mt < 2; mt++) {
      qf[mt][0] = *reinterpret_cast<const bf16x8_t*>(
          Qbase + (size_t)(qrow0 + mt * 16 + ln) * HD_ + quad * 8);
      qf[mt][1] = *reinterpret_cast<const bf16x8_t*>(
          Qbase + (size_t)(qrow0 + mt * 16 + ln) * HD_ + 32 + quad * 8);
    }

    f32x4_t O[2][4];
#pragma unroll
    for (int mt = 0; mt < 2; mt++)
#pragma unroll
      for (int dt = 0; dt < 4; dt++)
        O[mt][dt] = (f32x4_t){0.f, 0.f, 0.f, 0.f};
    float l[2][4];
#pragma unroll
    for (int mt = 0; mt < 2; mt++)
#pragma unroll
      for (int r = 0; r < 4; r++) l[mt][r] = 0.f;

    __syncthreads();   // prev-ti readers done; full vmcnt drain (incl. O stores)

    // stage steps 0 and 1 into bufs 0 and 1 (step-1 addresses always in-bounds)
    gload16(Kbase + (size_t)r0 * HD_ + c0 * 8,        &Kl[0][j0 * 512]);
    gload16(Kbase + (size_t)r1 * HD_ + c1 * 8,        &Kl[0][j1 * 512]);
    gload16(Vbase + (size_t)r0 * S_ + c0 * 8,         &Vl[0][j0 * 512]);
    gload16(Vbase + (size_t)r1 * S_ + c1 * 8,         &Vl[0][j1 * 512]);
    gload16(Kbase + (size_t)(64 + r0) * HD_ + c0 * 8, &Kl[1][j0 * 512]);
    gload16(Kbase + (size_t)(64 + r1) * HD_ + c1 * 8, &Kl[1][j1 * 512]);
    gload16(Vbase + (size_t)r0 * S_ + 64 + c0 * 8,    &Vl[1][j0 * 512]);
    gload16(Vbase + (size_t)r1 * S_ + 64 + c1 * 8,    &Vl[1][j1 * 512]);

    for (int step = 0; step < nsteps; ++step) {
      const int cur = step % 3;
      const int kv0 = step * 64;
      // counted wait: 4 gloads/stage; with stage(step+1) in flight, waiting
      // to 4 completes exactly stage(step). Tail drains to 0.
      if (step + 1 < nsteps) { asm volatile("s_waitcnt vmcnt(4)" ::: "memory"); }
      else                   { asm volatile("s_waitcnt vmcnt(0)" ::: "memory"); }
      __builtin_amdgcn_s_barrier();
      __builtin_amdgcn_sched_barrier(0);

      if (step + 2 < nsteps) {
        const int nb  = (step + 2) % 3;
        const int nkv = kv0 + 128;
        gload16(Kbase + (size_t)(nkv + r0) * HD_ + c0 * 8, &Kl[nb][j0 * 512]);
        gload16(Kbase + (size_t)(nkv + r1) * HD_ + c1 * 8, &Kl[nb][j1 * 512]);
        gload16(Vbase + (size_t)r0 * S_ + nkv + c0 * 8,    &Vl[nb][j0 * 512]);
        gload16(Vbase + (size_t)r1 * S_ + nkv + c1 * 8,    &Vl[nb][j1 * 512]);
      }

      const u16* Kc = Kl[cur];
      const u16* Vc = Vl[cur];

      bf16x8_t kf0[4], kf1[4];
#pragma unroll
      for (int kt = 0; kt < 4; kt++) {
        const u16* rp = Kc + (kt * 16 + ln) * 64;
        kf0[kt] = *reinterpret_cast<const bf16x8_t*>(rp + ck0 * 8);
        kf1[kt] = *reinterpret_cast<const bf16x8_t*>(rp + ck1 * 8);
      }
      f32x4_t s[2][4];
#pragma unroll
      for (int mt = 0; mt < 2; mt++)
#pragma unroll
        for (int kt = 0; kt < 4; kt++) {
          f32x4_t acc = (f32x4_t){0.f, 0.f, 0.f, 0.f};
          acc = __builtin_amdgcn_mfma_f32_16x16x32_bf16(qf[mt][0], kf0[kt], acc, 0, 0, 0);
          acc = __builtin_amdgcn_mfma_f32_16x16x32_bf16(qf[mt][1], kf1[kt], acc, 0, 0, 0);
          s[mt][kt] = acc;
        }

      bf16x8_t vf0[4], vf1[4];
#pragma unroll
      for (int dt = 0; dt < 4; dt++) {
        const u16* rp = Vc + (dt * 16 + ln) * 64;
        vf0[dt] = *reinterpret_cast<const bf16x8_t*>(rp + ck0 * 8);
        vf1[dt] = *reinterpret_cast<const bf16x8_t*>(rp + ck1 * 8);
      }

      if (kv0 + 63 > qrow0) {
#pragma unroll
        for (int mt = 0; mt < 2; mt++)
#pragma unroll
          for (int kt = 0; kt < 4; kt++)
#pragma unroll
            for (int r = 0; r < 4; r++) {
              int rowg = qrow0 + mt * 16 + quad * 4 + r;
              if (kv0 + kt * 16 + ln > rowg) s[mt][kt][r] = -1e30f;
            }
      }

#pragma unroll
      for (int mt = 0; mt < 2; mt++)
#pragma unroll
        for (int r = 0; r < 4; r++) {
          float p0f = __expf(s[mt][0][r] - MEXP);
          float p1f = __expf(s[mt][1][r] - MEXP);
          float p2f = __expf(s[mt][2][r] - MEXP);
          float p3f = __expf(s[mt][3][r] - MEXP);
          l[mt][r] += (p0f + p1f) + (p2f + p3f);
          ushort4 pk;   // truncation pack (bias cancels in O/l)
          pk.x = (u16)(__float_as_uint(p0f) >> 16);
          pk.y = (u16)(__float_as_uint(p1f) >> 16);
          pk.z = (u16)(__float_as_uint(p2f) >> 16);
          pk.w = (u16)(__float_as_uint(p3f) >> 16);
          *reinterpret_cast<ushort4*>(&Plds[wv][mt][quad * 4 + r][ln * 4]) = pk;
        }

#pragma unroll
      for (int mt = 0; mt < 2; mt++) {
        bf16x8_t pf0 = *reinterpret_cast<const bf16x8_t*>(&Plds[wv][mt][ln][quad * 8]);
        bf16x8_t pf1 = *reinterpret_cast<const bf16x8_t*>(&Plds[wv][mt][ln][32 + quad * 8]);
#pragma unroll
        for (int dt = 0; dt < 4; dt++) {
          O[mt][dt] = __builtin_amdgcn_mfma_f32_16x16x32_bf16(pf0, vf0[dt], O[mt][dt], 0, 0, 0);
          O[mt][dt] = __builtin_amdgcn_mfma_f32_16x16x32_bf16(pf1, vf1[dt], O[mt][dt], 0, 0, 0);
        }
      }
    }

#pragma unroll
    for (int mt = 0; mt < 2; mt++)
#pragma unroll
      for (int r = 0; r < 4; r++) {
        float lv = l[mt][r];
        lv += __shfl_xor(lv, 1);
        lv += __shfl_xor(lv, 2);
        lv += __shfl_xor(lv, 4);
        lv += __shfl_xor(lv, 8);
        float inv = 1.0f / lv;
        int srow = qrow0 + mt * 16 + quad * 4 + r;
        size_t base = ((size_t)b * S_ + srow) * (size_t)(NH_ * HD_) + h * HD_;
#pragma unroll
        for (int dt = 0; dt < 4; dt++)
          Og[base + dt * 16 + ln] = f2bf(O[mt][dt][r] * inv);
      }
  }
}

// ---------------- launch ----------------

extern "C" void kernel_launch(void* const* d_in, const int* in_sizes, int n_in,
                              void* d_out, int out_size, void* d_ws, size_t ws_size,
                              hipStream_t stream) {
  const float* x  = (const float*)d_in[0];
  const int*   pos = (const int*)d_in[1];
  const float* Wq = (const float*)d_in[2];
  const float* bq = (const float*)d_in[3];
  const float* Wk = (const float*)d_in[4];
  const float* bk = (const float*)d_in[5];
  const float* Wv = (const float*)d_in[6];
  const float* bv = (const float*)d_in[7];
  const float* Wo = (const float*)d_in[8];
  float* out = (float*)d_out;

  char* ws = (char*)d_ws;
  u16*   xb    = (u16*)(ws);                     // [4096][2048] bf16   16.8MB
  u16*   Wqkvt = (u16*)(ws + 16777216);          // [3072][2048] bf16   12.6MB
  u16*   Wot   = (u16*)(ws + 29360128);          // [2048][2048] bf16    8.4MB
  float* cosb  = (float*)(ws + 37748736);        // [4096][32] f32
  float* sinb  = (float*)(ws + 38797312);        // [4096][32] f32
  u16*   Qb    = (u16*)(ws + 39845888);          // [B][NH][S][HD]      16.8MB
  u16*   Kb    = (u16*)(ws + 56623104);          // [B][NKV][S][HD]      4.2MB
  u16*   Vtmp  = (u16*)(ws + 60817408);          // [4096][512] bf16     4.2MB
  u16*   Vt    = (u16*)(ws + 65011712);          // [B][NKV][HD][S]      4.2MB (kv-permuted)
  u16*   Og    = (u16*)(ws + 69206016);          // [4096][2048] bf16   16.8MB

  cvt_bf16<<<ROWS * H_ / 4 / 256, 256, 0, stream>>>(x, xb, ROWS * H_ / 4);
  transpose_wqkv<<<dim3(96, 64), dim3(32, 8), 0, stream>>>(Wq, Wk, Wv, Wqkvt);
  transpose_w<<<dim3(64, 64), dim3(32, 8), 0, stream>>>(Wo, Wot, 2048);
  cossin_k<<<ROWS * 32 / 256, 256, 0, stream>>>(pos, cosb, sinb);

  gemm256<0><<<dim3(16, 12), 512, 0, stream>>>(xb, Wqkvt, bq, bk, bv, cosb, sinb,
                                               Qb, Kb, Vtmp, nullptr, 0);

  prep_v<<<dim3(32, 16), 256, 0, stream>>>(Vtmp, Vt);

  flash_attn<<<dim3(32, 16), 256, 0, stream>>>(Qb, Kb, Vt, Og);

  gemm256<1><<<dim3(32, 8), 512, 0, stream>>>(Og, Wot, nullptr, nullptr, nullptr,
                                              nullptr, nullptr, nullptr, nullptr, nullptr,
                                              out, 2048);
}

// Round 5
// 307.004 us; speedup vs baseline: 1.0682x; 1.0013x over previous
//
#include <hip/hip_runtime.h>

#define B_   2
#define S_   2048
#define H_   2048
#define NH_  32
#define NKV_ 8
#define HD_  64
#define ROWS (B_*S_)   // 4096
#define MEXP 20.0f

typedef unsigned short u16;
typedef __bf16 bf16x8_t __attribute__((ext_vector_type(8)));
typedef float  f32x4_t  __attribute__((ext_vector_type(4)));

__device__ __forceinline__ u16 f2bf(float f) {
  union { float f; unsigned u; } v; v.f = f;
  unsigned u = v.u;
  u += 0x7FFFu + ((u >> 16) & 1u);
  return (u16)(u >> 16);
}

// async global->LDS, 16B per lane. LDS dest = wave-uniform base + lane*16.
__device__ __forceinline__ void gload16(const u16* g, u16* l) {
  __builtin_amdgcn_global_load_lds((const __attribute__((address_space(1))) void*)g,
                                   (__attribute__((address_space(3))) void*)l, 16, 0, 0);
}

// ---------------- elementwise converts / prep ----------------

__global__ void cvt_bf16(const float* __restrict__ src, u16* __restrict__ dst, int n4) {
  int i = blockIdx.x * 256 + threadIdx.x;
  if (i >= n4) return;
  float4 v = reinterpret_cast<const float4*>(src)[i];
  ushort4 o;
  o.x = f2bf(v.x); o.y = f2bf(v.y); o.z = f2bf(v.z); o.w = f2bf(v.w);
  reinterpret_cast<ushort4*>(dst)[i] = o;
}

// merged transpose of Wq|Wk|Wv -> Wqkvt [3072][2048] bf16. grid (96,64),(32,8)
__global__ void transpose_wqkv(const float* __restrict__ Wq, const float* __restrict__ Wk,
                               const float* __restrict__ Wv, u16* __restrict__ dst) {
  __shared__ float t[32][33];
  const int k0  = blockIdx.y * 32;
  const int n0g = blockIdx.x * 32;
  const float* src; int N, n0;
  if (n0g < 2048)      { src = Wq; N = 2048; n0 = n0g; }
  else if (n0g < 2560) { src = Wk; N = 512;  n0 = n0g - 2048; }
  else                 { src = Wv; N = 512;  n0 = n0g - 2560; }
  const int tx = threadIdx.x, ty = threadIdx.y;
#pragma unroll
  for (int i = 0; i < 32; i += 8)
    t[ty + i][tx] = src[(size_t)(k0 + ty + i) * N + n0 + tx];
  __syncthreads();
#pragma unroll
  for (int i = 0; i < 32; i += 8)
    dst[(size_t)(n0g + ty + i) * 2048 + k0 + tx] = f2bf(t[tx][ty + i]);
}

__global__ void transpose_w(const float* __restrict__ src, u16* __restrict__ dst, int N) {
  __shared__ float t[32][33];
  const int k0 = blockIdx.y * 32;
  const int n0 = blockIdx.x * 32;
  const int tx = threadIdx.x, ty = threadIdx.y;
#pragma unroll
  for (int i = 0; i < 32; i += 8)
    t[ty + i][tx] = src[(size_t)(k0 + ty + i) * N + n0 + tx];
  __syncthreads();
#pragma unroll
  for (int i = 0; i < 32; i += 8)
    dst[(size_t)(n0 + ty + i) * 2048 + k0 + tx] = f2bf(t[tx][ty + i]);
}

// cos/sin tables [ROWS][32] f32 (d < 32 only; d+32 shares values).
__global__ void cossin_k(const int* __restrict__ pos,
                         float* __restrict__ cosb, float* __restrict__ sinb) {
  int t = blockIdx.x * 256 + threadIdx.x;   // row*32 + d
  int row = t >> 5, d = t & 31;
  int sec = (d < 16) ? 0 : 1;
  float p = (float)pos[sec * ROWS + row];
  float inv_freq = powf(1.0e6f, -(float)d * (1.0f / 32.0f));
  float fr = p * inv_freq;
  float s, c;
  sincosf(fr, &s, &c);
  cosb[t] = c;
  sinb[t] = s;
}

// ---------------- BK=64 8-phase pipelined GEMM (T2+T3+T4+T5) ----------------
// MODE 0: 256x256 tile, grid 16x12=192 blocks, fused bias+mRoPE QKV epilogue.
// MODE 1: 128x256 tile, grid 32x8 =256 blocks (exact fill), plain f32 store.
// Natural block order. 8 waves (2M x 4N); per K-tile: MF/2 phases of 16 MFMA
// each; A(kt+1) staged in phase 0, B(kt+2) in later phases; counted vmcnt(4)
// at last phase. LDS chunk swizzle: chunk ^= (row&7); source pre-swizzled.

#define BAR() { __builtin_amdgcn_s_barrier(); __builtin_amdgcn_sched_barrier(0); }

#define STG(G, L, RB, h, kt) { \
    const u16* g_ = (G) + (size_t)((RB) + (h) * 128 + srow) * 2048 + (kt) * 64 + sc8; \
    gload16(g_,             (L) + (h) * 8192 + sldo);       \
    gload16(g_ + 8 * 2048,  (L) + (h) * 8192 + sldo + 512); }

#define LDAF(mm) \
    af[0][0] = *reinterpret_cast<const bf16x8_t*>(Asp + rowxA + (mm) * 1024 + cof0); \
    af[0][1] = *reinterpret_cast<const bf16x8_t*>(Asp + rowxA + (mm) * 1024 + cof1); \
    af[1][0] = *reinterpret_cast<const bf16x8_t*>(Asp + rowxA + (mm) * 1024 + 1024 + cof0); \
    af[1][1] = *reinterpret_cast<const bf16x8_t*>(Asp + rowxA + (mm) * 1024 + 1024 + cof1);

#define MFMA8(mb) \
    _Pragma("unroll") \
    for (int n = 0; n < 4; ++n) { \
      acc[(mb)][n]     = __builtin_amdgcn_mfma_f32_16x16x32_bf16(af[0][0], bfr[n][0], acc[(mb)][n], 0, 0, 0); \
      acc[(mb)][n]     = __builtin_amdgcn_mfma_f32_16x16x32_bf16(af[0][1], bfr[n][1], acc[(mb)][n], 0, 0, 0); \
      acc[(mb) + 1][n] = __builtin_amdgcn_mfma_f32_16x16x32_bf16(af[1][0], bfr[n][0], acc[(mb) + 1][n], 0, 0, 0); \
      acc[(mb) + 1][n] = __builtin_amdgcn_mfma_f32_16x16x32_bf16(af[1][1], bfr[n][1], acc[(mb) + 1][n], 0, 0, 0); \
    }

template <int MODE>
__global__ __launch_bounds__(512, 2) void gemm256(
    const u16* __restrict__ A, const u16* __restrict__ Bt,
    const float* __restrict__ bq, const float* __restrict__ bk, const float* __restrict__ bv,
    const float* __restrict__ cosb, const float* __restrict__ sinb,
    u16* __restrict__ Qb, u16* __restrict__ Kb, u16* __restrict__ Vtmp,
    float* __restrict__ Cout, int Nout) {
  constexpr int BMx = (MODE == 0) ? 256 : 128;   // M tile
  constexpr int MF  = BMx / 32;                  // per-wave m-frags (8 or 4)

  const int m0 = blockIdx.x * BMx;
  const int n0 = blockIdx.y * 256;

  __shared__ __align__(16) u16 As[2][BMx * 64];
  __shared__ __align__(16) u16 Bs[2][16384];
  const int tid  = threadIdx.x;
  const int lane = tid & 63;
  const int wv   = tid >> 6;        // 0..7
  const int wr   = wv >> 2;         // 0..1  (M half)
  const int wc   = wv & 3;          // 0..3  (N quarter)
  const int ln   = lane & 15;
  const int quad = lane >> 4;

  const int srow = wv * 16 + (lane >> 3);            // row within half (2nd gload +8)
  const int sc8  = ((lane & 7) ^ (lane >> 3)) * 8;   // pre-swizzled k-chunk (u16)
  const int sldo = wv * 1024;                        // u16 offset of wave slice

  const int rowxA = (wr * (BMx / 2) + ln) * 64;
  const int rowxB = (wc * 64       + ln) * 64;
  const int cof0  = ((quad    ) ^ (ln & 7)) * 8;     // kk=0 chunk = quad
  const int cof1  = ((quad ^ 4) ^ (ln & 7)) * 8;     // kk=1 chunk = 4+quad

  f32x4_t acc[MF][4];
#pragma unroll
  for (int i = 0; i < MF; i++)
#pragma unroll
    for (int j = 0; j < 4; j++)
      acc[i][j] = (f32x4_t){0.f, 0.f, 0.f, 0.f};

  STG(A, As[0], m0, 0, 0);
  if constexpr (MODE == 0) { STG(A, As[0], m0, 1, 0); }
  STG(Bt, Bs[0], n0, 0, 0); STG(Bt, Bs[0], n0, 1, 0);
  STG(Bt, Bs[1], n0, 0, 1); STG(Bt, Bs[1], n0, 1, 1);
  asm volatile("s_waitcnt vmcnt(4)" ::: "memory");
  BAR();

  for (int kt = 0; kt < 32; ++kt) {
    const int par = kt & 1;
    const u16* Asp = As[par];
    const u16* Bsp = Bs[par];
    u16* Asn = As[par ^ 1];
    u16* Bsn = Bs[par];               // B(kt+2) has same parity as B(kt)
    bf16x8_t bfr[4][2], af[2][2];

    if constexpr (MODE == 0) {
#pragma unroll
      for (int n = 0; n < 4; ++n) {
        bfr[n][0] = *reinterpret_cast<const bf16x8_t*>(Bsp + rowxB + n * 1024 + cof0);
        bfr[n][1] = *reinterpret_cast<const bf16x8_t*>(Bsp + rowxB + n * 1024 + cof1);
      }
      LDAF(0);
      if (kt + 1 < 32) { STG(A, Asn, m0, 0, kt + 1); STG(A, Asn, m0, 1, kt + 1); }
      BAR();
      __builtin_amdgcn_s_setprio(1);
      MFMA8(0);
      __builtin_amdgcn_s_setprio(0);
      BAR();

      LDAF(2);
      if (kt + 2 < 32) { STG(Bt, Bsn, n0, 0, kt + 2); }
      BAR();
      __builtin_amdgcn_s_setprio(1);
      MFMA8(2);
      __builtin_amdgcn_s_setprio(0);
      BAR();

      LDAF(4);
      if (kt + 2 < 32) { STG(Bt, Bsn, n0, 1, kt + 2); }
      BAR();
      __builtin_amdgcn_s_setprio(1);
      MFMA8(4);
      __builtin_amdgcn_s_setprio(0);
      BAR();

      LDAF(6);
      BAR();
      __builtin_amdgcn_s_setprio(1);
      MFMA8(6);
      __builtin_amdgcn_s_setprio(0);
      if (kt + 2 < 32) { asm volatile("s_waitcnt vmcnt(4)" ::: "memory"); }
      else             { asm volatile("s_waitcnt vmcnt(0)" ::: "memory"); }
      BAR();
    } else {
#pragma unroll
      for (int n = 0; n < 4; ++n) {
        bfr[n][0] = *reinterpret_cast<const bf16x8_t*>(Bsp + rowxB + n * 1024 + cof0);
        bfr[n][1] = *reinterpret_cast<const bf16x8_t*>(Bsp + rowxB + n * 1024 + cof1);
      }
      LDAF(0);
      if (kt + 1 < 32) { STG(A, Asn, m0, 0, kt + 1); }
      BAR();
      __builtin_amdgcn_s_setprio(1);
      MFMA8(0);
      __builtin_amdgcn_s_setprio(0);
      BAR();

      LDAF(2);
      if (kt + 2 < 32) { STG(Bt, Bsn, n0, 0, kt + 2); STG(Bt, Bsn, n0, 1, kt + 2); }
      BAR();
      __builtin_amdgcn_s_setprio(1);
      MFMA8(2);
      __builtin_amdgcn_s_setprio(0);
      if (kt + 2 < 32) { asm volatile("s_waitcnt vmcnt(4)" ::: "memory"); }
      else             { asm volatile("s_waitcnt vmcnt(0)" ::: "memory"); }
      BAR();
    }
  }

  if constexpr (MODE == 0) {
    const int colbase = n0 + wc * 64;   // multiple of 64 -> one head per wave
    if (n0 < 2048) {
      const int hq = colbase >> 6;
#pragma unroll
      for (int i = 0; i < MF; i++) {
        int rw0 = m0 + wr * (BMx / 2) + i * 16 + quad * 4;
#pragma unroll
        for (int j = 0; j < 2; j++) {
          int d = j * 16 + ln;     // < 32
          float b0 = bq[colbase + d];
          float b1 = bq[colbase + d + 32];
#pragma unroll
          for (int r = 0; r < 4; r++) {
            int row = rw0 + r;
            float c  = cosb[row * 32 + d];
            float sn = sinb[row * 32 + d];
            float v0 = acc[i][j][r]     + b0;
            float v1 = acc[i][j + 2][r] + b1;
            int bb = row >> 11, s = row & (S_ - 1);
            size_t base = ((size_t)(bb * NH_ + hq) * S_ + s) * HD_;
            Qb[base + d]      = f2bf((v0 * c - v1 * sn) * 0.125f);
            Qb[base + d + 32] = f2bf((v1 * c + v0 * sn) * 0.125f);
          }
        }
      }
    } else if (n0 < 2560) {
      const int kh = (colbase - 2048) >> 6;
#pragma unroll
      for (int i = 0; i < MF; i++) {
        int rw0 = m0 + wr * (BMx / 2) + i * 16 + quad * 4;
#pragma unroll
        for (int j = 0; j < 2; j++) {
          int d = j * 16 + ln;
          float b0 = bk[(colbase - 2048) + d];
          float b1 = bk[(colbase - 2048) + d + 32];
#pragma unroll
          for (int r = 0; r < 4; r++) {
            int row = rw0 + r;
            float c  = cosb[row * 32 + d];
            float sn = sinb[row * 32 + d];
            float v0 = acc[i][j][r]     + b0;
            float v1 = acc[i][j + 2][r] + b1;
            int bb = row >> 11, s = row & (S_ - 1);
            size_t base = ((size_t)(bb * NKV_ + kh) * S_ + s) * HD_;
            Kb[base + d]      = f2bf(v0 * c - v1 * sn);
            Kb[base + d + 32] = f2bf(v1 * c + v0 * sn);
          }
        }
      }
    } else {
#pragma unroll
      for (int i = 0; i < MF; i++) {
        int rw0 = m0 + wr * (BMx / 2) + i * 16 + quad * 4;
#pragma unroll
        for (int j = 0; j < 4; j++) {
          int cv = colbase - 2560 + j * 16 + ln;
          float bvv = bv[cv];
#pragma unroll
          for (int r = 0; r < 4; r++)
            Vtmp[(size_t)(rw0 + r) * 512 + cv] = f2bf(acc[i][j][r] + bvv);
        }
      }
    }
  } else {
#pragma unroll
    for (int i = 0; i < MF; i++) {
      int row = m0 + wr * (BMx / 2) + i * 16 + quad * 4;
#pragma unroll
      for (int j = 0; j < 4; j++) {
        int col = n0 + wc * 64 + j * 16 + ln;
        float* cp = Cout + (size_t)row * Nout + col;
#pragma unroll
        for (int r = 0; r < 4; r++)
          cp[(size_t)r * Nout] = acc[i][j][r];
      }
    }
  }
}

// V^T with kv-permuted columns from bf16 Vtmp [4096][512].
__global__ void prep_v(const u16* __restrict__ Vtmp, u16* __restrict__ Vt) {
  __shared__ u16 tile[64][65];
  const int sb  = blockIdx.x * 64;
  const int bk  = blockIdx.y;
  const int b   = bk >> 3, kvh = bk & 7;
  const int tx  = threadIdx.x & 63;
  const int ty  = threadIdx.x >> 6;   // 0..3
  const u16* src = Vtmp + (size_t)(b * 2048 + sb) * 512 + kvh * 64;
#pragma unroll
  for (int i = ty; i < 64; i += 4)
    tile[i][tx] = src[(size_t)i * 512 + tx];
  __syncthreads();
  const int sp = sb + (tx & 15) * 4 + (tx >> 4);   // permuted col
  u16* dst = Vt + (size_t)(b * NKV_ + kvh) * HD_ * (size_t)S_;
#pragma unroll
  for (int j = ty; j < 64; j += 4)
    dst[(size_t)j * S_ + sp] = tile[tx][j];
}

// ---------------- causal GQA flash attention ----------------
// v8: merged q-tile pair. Each block owns tiles {u, 63-u}; since tile u's KV
// range is a subset of tile (63-u)'s, both are computed CONCURRENTLY in one
// KV stream: staged K/V and kf LDS reads shared; steps per block drop from
// (u/2+1)+((63-u)/2+1)=33 to (63-u)/2+1 (avg 24.75, -25% staging).
// Per-CU balance: u = (y<8) ? x : 31-x pairs complementary lengths on the
// co-resident block (c, c+256). 3-buffer ring, counted vmcnt(4) (T3/T4).
__device__ __forceinline__ void attn_tile(
    const bf16x8_t (&qf)[2][2], f32x4_t (&O)[2][4], float (&l)[2][4],
    const bf16x8_t* kf0, const bf16x8_t* kf1,
    const u16* Vc, int ck0, int ck1,
    u16* plds, int qrow0, int kv0, int ln, int quad) {
  f32x4_t s[2][4];
#pragma unroll
  for (int mt = 0; mt < 2; mt++)
#pragma unroll
    for (int kt = 0; kt < 4; kt++) {
      f32x4_t a = (f32x4_t){0.f, 0.f, 0.f, 0.f};
      a = __builtin_amdgcn_mfma_f32_16x16x32_bf16(qf[mt][0], kf0[kt], a, 0, 0, 0);
      a = __builtin_amdgcn_mfma_f32_16x16x32_bf16(qf[mt][1], kf1[kt], a, 0, 0, 0);
      s[mt][kt] = a;
    }
  if (kv0 + 63 > qrow0) {
#pragma unroll
    for (int mt = 0; mt < 2; mt++)
#pragma unroll
      for (int kt = 0; kt < 4; kt++)
#pragma unroll
        for (int r = 0; r < 4; r++) {
          int rowg = qrow0 + mt * 16 + quad * 4 + r;
          if (kv0 + kt * 16 + ln > rowg) s[mt][kt][r] = -1e30f;
        }
  }
#pragma unroll
  for (int mt = 0; mt < 2; mt++)
#pragma unroll
    for (int r = 0; r < 4; r++) {
      float p0f = __expf(s[mt][0][r] - MEXP);
      float p1f = __expf(s[mt][1][r] - MEXP);
      float p2f = __expf(s[mt][2][r] - MEXP);
      float p3f = __expf(s[mt][3][r] - MEXP);
      l[mt][r] += (p0f + p1f) + (p2f + p3f);
      ushort4 pk;   // truncation pack (bias cancels in O/l)
      pk.x = (u16)(__float_as_uint(p0f) >> 16);
      pk.y = (u16)(__float_as_uint(p1f) >> 16);
      pk.z = (u16)(__float_as_uint(p2f) >> 16);
      pk.w = (u16)(__float_as_uint(p3f) >> 16);
      *reinterpret_cast<ushort4*>(&plds[mt * 1152 + (quad * 4 + r) * 72 + ln * 4]) = pk;
    }
#pragma unroll
  for (int mt = 0; mt < 2; mt++) {
    bf16x8_t pf0 = *reinterpret_cast<const bf16x8_t*>(&plds[mt * 1152 + ln * 72 + quad * 8]);
    bf16x8_t pf1 = *reinterpret_cast<const bf16x8_t*>(&plds[mt * 1152 + ln * 72 + 32 + quad * 8]);
#pragma unroll
    for (int dt = 0; dt < 4; dt++) {
      const u16* rp = Vc + (dt * 16 + ln) * 64;
      bf16x8_t v0 = *reinterpret_cast<const bf16x8_t*>(rp + ck0 * 8);
      bf16x8_t v1 = *reinterpret_cast<const bf16x8_t*>(rp + ck1 * 8);
      O[mt][dt] = __builtin_amdgcn_mfma_f32_16x16x32_bf16(pf0, v0, O[mt][dt], 0, 0, 0);
      O[mt][dt] = __builtin_amdgcn_mfma_f32_16x16x32_bf16(pf1, v1, O[mt][dt], 0, 0, 0);
    }
  }
}

__global__ __launch_bounds__(256, 2) void flash_attn(
    const u16* __restrict__ Qb, const u16* __restrict__ Kb, const u16* __restrict__ Vt,
    u16* __restrict__ Og) {
  const int bkk  = blockIdx.y;
  const int b    = bkk >> 3;
  const int kvh  = bkk & 7;
  const int u    = (bkk < 8) ? blockIdx.x : (31 - blockIdx.x);
  const int tid  = threadIdx.x;
  const int wv   = tid >> 6;
  const int h    = kvh * 4 + wv;
  const int lane = tid & 63;
  const int ln   = lane & 15;
  const int quad = lane >> 4;

  __shared__ __align__(16) u16 Kl[3][64 * 64];
  __shared__ __align__(16) u16 Vl[3][64 * 64];
  __shared__ __align__(16) u16 Plds[4][2][16][72];
  u16* plds = &Plds[wv][0][0][0];

  const u16* Qbase = Qb + ((size_t)(b * NH_ + h) * S_) * HD_;
  const u16* Kbase = Kb + ((size_t)(b * NKV_ + kvh) * S_) * HD_;
  const u16* Vbase = Vt + ((size_t)(b * NKV_ + kvh) * HD_) * S_;

  const int j0 = wv * 2, j1 = wv * 2 + 1;
  const int p0 = j0 * 64 + lane,  p1 = j1 * 64 + lane;
  const int r0 = p0 >> 3,  c0 = (p0 & 7) ^ (r0 & 7);
  const int r1 = p1 >> 3,  c1 = (p1 & 7) ^ (r1 & 7);

  const int sw  = ln & 7;
  const int ck0 = quad ^ sw;
  const int ck1 = ck0 ^ 4;

  const int tB = u, tA = 63 - u;           // tA >= 32 > tB
  const int qrowB = tB * 32, qrowA = tA * 32;
  const int nstepsB = tB / 2 + 1;
  const int nsteps  = tA / 2 + 1;          // >= 17

  bf16x8_t qfA[2][2], qfB[2][2];
#pragma unroll
  for (int mt = 0; mt < 2; mt++) {
    qfB[mt][0] = *reinterpret_cast<const bf16x8_t*>(
        Qbase + (size_t)(qrowB + mt * 16 + ln) * HD_ + quad * 8);
    qfB[mt][1] = *reinterpret_cast<const bf16x8_t*>(
        Qbase + (size_t)(qrowB + mt * 16 + ln) * HD_ + 32 + quad * 8);
    qfA[mt][0] = *reinterpret_cast<const bf16x8_t*>(
        Qbase + (size_t)(qrowA + mt * 16 + ln) * HD_ + quad * 8);
    qfA[mt][1] = *reinterpret_cast<const bf16x8_t*>(
        Qbase + (size_t)(qrowA + mt * 16 + ln) * HD_ + 32 + quad * 8);
  }

  f32x4_t OA[2][4], OB[2][4];
  float lA[2][4], lB[2][4];
#pragma unroll
  for (int mt = 0; mt < 2; mt++)
#pragma unroll
    for (int dt = 0; dt < 4; dt++) {
      OA[mt][dt] = (f32x4_t){0.f, 0.f, 0.f, 0.f};
      OB[mt][dt] = (f32x4_t){0.f, 0.f, 0.f, 0.f};
      lA[mt][dt] = 0.f; lB[mt][dt] = 0.f;
    }

  // stage steps 0 and 1 into bufs 0 and 1 (nsteps >= 17, both in-bounds)
  gload16(Kbase + (size_t)r0 * HD_ + c0 * 8,        &Kl[0][j0 * 512]);
  gload16(Kbase + (size_t)r1 * HD_ + c1 * 8,        &Kl[0][j1 * 512]);
  gload16(Vbase + (size_t)r0 * S_ + c0 * 8,         &Vl[0][j0 * 512]);
  gload16(Vbase + (size_t)r1 * S_ + c1 * 8,         &Vl[0][j1 * 512]);
  gload16(Kbase + (size_t)(64 + r0) * HD_ + c0 * 8, &Kl[1][j0 * 512]);
  gload16(Kbase + (size_t)(64 + r1) * HD_ + c1 * 8, &Kl[1][j1 * 512]);
  gload16(Vbase + (size_t)r0 * S_ + 64 + c0 * 8,    &Vl[1][j0 * 512]);
  gload16(Vbase + (size_t)r1 * S_ + 64 + c1 * 8,    &Vl[1][j1 * 512]);

  for (int step = 0; step < nsteps; ++step) {
    const int cur = step % 3;
    const int kv0 = step * 64;
    // counted wait: 4 gloads/stage; with stage(step+1) in flight, waiting
    // to 4 completes exactly stage(step). Tail drains to 0.
    if (step + 1 < nsteps) { asm volatile("s_waitcnt vmcnt(4)" ::: "memory"); }
    else                   { asm volatile("s_waitcnt vmcnt(0)" ::: "memory"); }
    __builtin_amdgcn_s_barrier();
    __builtin_amdgcn_sched_barrier(0);

    if (step + 2 < nsteps) {
      const int nb  = (step + 2) % 3;
      const int nkv = kv0 + 128;
      gload16(Kbase + (size_t)(nkv + r0) * HD_ + c0 * 8, &Kl[nb][j0 * 512]);
      gload16(Kbase + (size_t)(nkv + r1) * HD_ + c1 * 8, &Kl[nb][j1 * 512]);
      gload16(Vbase + (size_t)r0 * S_ + nkv + c0 * 8,    &Vl[nb][j0 * 512]);
      gload16(Vbase + (size_t)r1 * S_ + nkv + c1 * 8,    &Vl[nb][j1 * 512]);
    }

    const u16* Kc = Kl[cur];
    const u16* Vc = Vl[cur];

    bf16x8_t kf0[4], kf1[4];
#pragma unroll
    for (int kt = 0; kt < 4; kt++) {
      const u16* rp = Kc + (kt * 16 + ln) * 64;
      kf0[kt] = *reinterpret_cast<const bf16x8_t*>(rp + ck0 * 8);
      kf1[kt] = *reinterpret_cast<const bf16x8_t*>(rp + ck1 * 8);
    }

    attn_tile(qfA, OA, lA, kf0, kf1, Vc, ck0, ck1, plds, qrowA, kv0, ln, quad);
    if (step < nstepsB)
      attn_tile(qfB, OB, lB, kf0, kf1, Vc, ck0, ck1, plds, qrowB, kv0, ln, quad);
  }

#define EPI(Ox, lx, QR) \
  _Pragma("unroll") \
  for (int mt = 0; mt < 2; mt++) \
    _Pragma("unroll") \
    for (int r = 0; r < 4; r++) { \
      float lv = lx[mt][r]; \
      lv += __shfl_xor(lv, 1); \
      lv += __shfl_xor(lv, 2); \
      lv += __shfl_xor(lv, 4); \
      lv += __shfl_xor(lv, 8); \
      float inv = 1.0f / lv; \
      int srow = (QR) + mt * 16 + quad * 4 + r; \
      size_t base = ((size_t)b * S_ + srow) * (size_t)(NH_ * HD_) + h * HD_; \
      _Pragma("unroll") \
      for (int dt = 0; dt < 4; dt++) \
        Og[base + dt * 16 + ln] = f2bf(Ox[mt][dt][r] * inv); \
    }

  EPI(OA, lA, qrowA);
  EPI(OB, lB, qrowB);
#undef EPI
}

// ---------------- launch ----------------

extern "C" void kernel_launch(void* const* d_in, const int* in_sizes, int n_in,
                              void* d_out, int out_size, void* d_ws, size_t ws_size,
                              hipStream_t stream) {
  const float* x  = (const float*)d_in[0];
  const int*   pos = (const int*)d_in[1];
  const float* Wq = (const float*)d_in[2];
  const float* bq = (const float*)d_in[3];
  const float* Wk = (const float*)d_in[4];
  const float* bk = (const float*)d_in[5];
  const float* Wv = (const float*)d_in[6];
  const float* bv = (const float*)d_in[7];
  const float* Wo = (const float*)d_in[8];
  float* out = (float*)d_out;

  char* ws = (char*)d_ws;
  u16*   xb    = (u16*)(ws);                     // [4096][2048] bf16   16.8MB
  u16*   Wqkvt = (u16*)(ws + 16777216);          // [3072][2048] bf16   12.6MB
  u16*   Wot   = (u16*)(ws + 29360128);          // [2048][2048] bf16    8.4MB
  float* cosb  = (float*)(ws + 37748736);        // [4096][32] f32
  float* sinb  = (float*)(ws + 38797312);        // [4096][32] f32
  u16*   Qb    = (u16*)(ws + 39845888);          // [B][NH][S][HD]      16.8MB
  u16*   Kb    = (u16*)(ws + 56623104);          // [B][NKV][S][HD]      4.2MB
  u16*   Vtmp  = (u16*)(ws + 60817408);          // [4096][512] bf16     4.2MB
  u16*   Vt    = (u16*)(ws + 65011712);          // [B][NKV][HD][S]      4.2MB (kv-permuted)
  u16*   Og    = (u16*)(ws + 69206016);          // [4096][2048] bf16   16.8MB

  cvt_bf16<<<ROWS * H_ / 4 / 256, 256, 0, stream>>>(x, xb, ROWS * H_ / 4);
  transpose_wqkv<<<dim3(96, 64), dim3(32, 8), 0, stream>>>(Wq, Wk, Wv, Wqkvt);
  transpose_w<<<dim3(64, 64), dim3(32, 8), 0, stream>>>(Wo, Wot, 2048);
  cossin_k<<<ROWS * 32 / 256, 256, 0, stream>>>(pos, cosb, sinb);

  gemm256<0><<<dim3(16, 12), 512, 0, stream>>>(xb, Wqkvt, bq, bk, bv, cosb, sinb,
                                               Qb, Kb, Vtmp, nullptr, 0);

  prep_v<<<dim3(32, 16), 256, 0, stream>>>(Vtmp, Vt);

  flash_attn<<<dim3(32, 16), 256, 0, stream>>>(Qb, Kb, Vt, Og);

  gemm256<1><<<dim3(32, 8), 512, 0, stream>>>(Og, Wot, nullptr, nullptr, nullptr,
                                              nullptr, nullptr, nullptr, nullptr, nullptr,
                                              out, 2048);
}

// Round 6
// 299.253 us; speedup vs baseline: 1.0959x; 1.0259x over previous
//
#include <hip/hip_runtime.h>

#define B_   2
#define S_   2048
#define H_   2048
#define NH_  32
#define NKV_ 8
#define HD_  64
#define ROWS (B_*S_)   // 4096
#define MEXP 20.0f

typedef unsigned short u16;
typedef __bf16 bf16x8_t __attribute__((ext_vector_type(8)));
typedef float  f32x4_t  __attribute__((ext_vector_type(4)));

__device__ __forceinline__ u16 f2bf(float f) {
  union { float f; unsigned u; } v; v.f = f;
  unsigned u = v.u;
  u += 0x7FFFu + ((u >> 16) & 1u);
  return (u16)(u >> 16);
}

// async global->LDS, 16B per lane. LDS dest = wave-uniform base + lane*16.
__device__ __forceinline__ void gload16(const u16* g, u16* l) {
  __builtin_amdgcn_global_load_lds((const __attribute__((address_space(1))) void*)g,
                                   (__attribute__((address_space(3))) void*)l, 16, 0, 0);
}

// ---------------- fused input prep: cvt | transpose_wqkv | transpose_w | cossin ----------------
// One launch instead of four (launch-gap reduction). Sections by blockIdx:
//   [0,8192)            cvt_bf16 of x           (8192 x 256 x float4)
//   [8192,14336)        Wq|Wk|Wv -> Wqkvt^T     (orig grid 96x64)
//   [14336,18432)       Wo -> Wot^T             (orig grid 64x64)
//   [18432,18944)       cos/sin tables          (512 x 256)
__global__ void prep_all(const float* __restrict__ x, u16* __restrict__ xb,
                         const float* __restrict__ Wq, const float* __restrict__ Wk,
                         const float* __restrict__ Wv, u16* __restrict__ Wqkvt,
                         const float* __restrict__ Wo, u16* __restrict__ Wot,
                         const int* __restrict__ pos,
                         float* __restrict__ cosb, float* __restrict__ sinb) {
  __shared__ float t[32][33];
  int bid = blockIdx.x;
  if (bid < 8192) {
    int i = bid * 256 + threadIdx.x;
    float4 v = reinterpret_cast<const float4*>(x)[i];
    ushort4 o;
    o.x = f2bf(v.x); o.y = f2bf(v.y); o.z = f2bf(v.z); o.w = f2bf(v.w);
    reinterpret_cast<ushort4*>(xb)[i] = o;
    return;
  }
  bid -= 8192;
  const int tx = threadIdx.x & 31, ty = threadIdx.x >> 5;   // (32,8)
  if (bid < 6144) {
    const int bx = bid % 96, by = bid / 96;
    const int k0  = by * 32;
    const int n0g = bx * 32;
    const float* src; int N, n0;
    if (n0g < 2048)      { src = Wq; N = 2048; n0 = n0g; }
    else if (n0g < 2560) { src = Wk; N = 512;  n0 = n0g - 2048; }
    else                 { src = Wv; N = 512;  n0 = n0g - 2560; }
#pragma unroll
    for (int i = 0; i < 32; i += 8)
      t[ty + i][tx] = src[(size_t)(k0 + ty + i) * N + n0 + tx];
    __syncthreads();
#pragma unroll
    for (int i = 0; i < 32; i += 8)
      Wqkvt[(size_t)(n0g + ty + i) * 2048 + k0 + tx] = f2bf(t[tx][ty + i]);
    return;
  }
  bid -= 6144;
  if (bid < 4096) {
    const int bx = bid % 64, by = bid / 64;
    const int k0 = by * 32;
    const int n0 = bx * 32;
#pragma unroll
    for (int i = 0; i < 32; i += 8)
      t[ty + i][tx] = Wo[(size_t)(k0 + ty + i) * 2048 + n0 + tx];
    __syncthreads();
#pragma unroll
    for (int i = 0; i < 32; i += 8)
      Wot[(size_t)(n0 + ty + i) * 2048 + k0 + tx] = f2bf(t[tx][ty + i]);
    return;
  }
  bid -= 4096;
  {
    int tt = bid * 256 + threadIdx.x;   // row*32 + d
    int row = tt >> 5, d = tt & 31;
    int sec = (d < 16) ? 0 : 1;
    float p = (float)pos[sec * ROWS + row];
    float inv_freq = powf(1.0e6f, -(float)d * (1.0f / 32.0f));
    float fr = p * inv_freq;
    float s, c;
    sincosf(fr, &s, &c);
    cosb[tt] = c;
    sinb[tt] = s;
  }
}

// ---------------- BK=64 8-phase pipelined GEMM (T2+T3+T4+T5) ----------------
// MODE 0: 256x256 tile, grid 16x12=192 blocks, fused bias+mRoPE QKV epilogue.
// MODE 1: 128x256 tile, grid 32x8 =256 blocks (exact fill), plain f32 store.
// Natural block order. 8 waves (2M x 4N); per K-tile: MF/2 phases of 16 MFMA
// each; A(kt+1) staged in phase 0, B(kt+2) in later phases; counted vmcnt(4)
// at last phase. LDS chunk swizzle: chunk ^= (row&7); source pre-swizzled.

#define BAR() { __builtin_amdgcn_s_barrier(); __builtin_amdgcn_sched_barrier(0); }

#define STG(G, L, RB, h, kt) { \
    const u16* g_ = (G) + (size_t)((RB) + (h) * 128 + srow) * 2048 + (kt) * 64 + sc8; \
    gload16(g_,             (L) + (h) * 8192 + sldo);       \
    gload16(g_ + 8 * 2048,  (L) + (h) * 8192 + sldo + 512); }

#define LDAF(mm) \
    af[0][0] = *reinterpret_cast<const bf16x8_t*>(Asp + rowxA + (mm) * 1024 + cof0); \
    af[0][1] = *reinterpret_cast<const bf16x8_t*>(Asp + rowxA + (mm) * 1024 + cof1); \
    af[1][0] = *reinterpret_cast<const bf16x8_t*>(Asp + rowxA + (mm) * 1024 + 1024 + cof0); \
    af[1][1] = *reinterpret_cast<const bf16x8_t*>(Asp + rowxA + (mm) * 1024 + 1024 + cof1);

#define MFMA8(mb) \
    _Pragma("unroll") \
    for (int n = 0; n < 4; ++n) { \
      acc[(mb)][n]     = __builtin_amdgcn_mfma_f32_16x16x32_bf16(af[0][0], bfr[n][0], acc[(mb)][n], 0, 0, 0); \
      acc[(mb)][n]     = __builtin_amdgcn_mfma_f32_16x16x32_bf16(af[0][1], bfr[n][1], acc[(mb)][n], 0, 0, 0); \
      acc[(mb) + 1][n] = __builtin_amdgcn_mfma_f32_16x16x32_bf16(af[1][0], bfr[n][0], acc[(mb) + 1][n], 0, 0, 0); \
      acc[(mb) + 1][n] = __builtin_amdgcn_mfma_f32_16x16x32_bf16(af[1][1], bfr[n][1], acc[(mb) + 1][n], 0, 0, 0); \
    }

template <int MODE>
__global__ __launch_bounds__(512, 2) void gemm256(
    const u16* __restrict__ A, const u16* __restrict__ Bt,
    const float* __restrict__ bq, const float* __restrict__ bk, const float* __restrict__ bv,
    const float* __restrict__ cosb, const float* __restrict__ sinb,
    u16* __restrict__ Qb, u16* __restrict__ Kb, u16* __restrict__ Vtmp,
    float* __restrict__ Cout, int Nout) {
  constexpr int BMx = (MODE == 0) ? 256 : 128;   // M tile
  constexpr int MF  = BMx / 32;                  // per-wave m-frags (8 or 4)

  const int m0 = blockIdx.x * BMx;
  const int n0 = blockIdx.y * 256;

  __shared__ __align__(16) u16 As[2][BMx * 64];
  __shared__ __align__(16) u16 Bs[2][16384];
  const int tid  = threadIdx.x;
  const int lane = tid & 63;
  const int wv   = tid >> 6;        // 0..7
  const int wr   = wv >> 2;         // 0..1  (M half)
  const int wc   = wv & 3;          // 0..3  (N quarter)
  const int ln   = lane & 15;
  const int quad = lane >> 4;

  const int srow = wv * 16 + (lane >> 3);            // row within half (2nd gload +8)
  const int sc8  = ((lane & 7) ^ (lane >> 3)) * 8;   // pre-swizzled k-chunk (u16)
  const int sldo = wv * 1024;                        // u16 offset of wave slice

  const int rowxA = (wr * (BMx / 2) + ln) * 64;
  const int rowxB = (wc * 64       + ln) * 64;
  const int cof0  = ((quad    ) ^ (ln & 7)) * 8;     // kk=0 chunk = quad
  const int cof1  = ((quad ^ 4) ^ (ln & 7)) * 8;     // kk=1 chunk = 4+quad

  f32x4_t acc[MF][4];
#pragma unroll
  for (int i = 0; i < MF; i++)
#pragma unroll
    for (int j = 0; j < 4; j++)
      acc[i][j] = (f32x4_t){0.f, 0.f, 0.f, 0.f};

  STG(A, As[0], m0, 0, 0);
  if constexpr (MODE == 0) { STG(A, As[0], m0, 1, 0); }
  STG(Bt, Bs[0], n0, 0, 0); STG(Bt, Bs[0], n0, 1, 0);
  STG(Bt, Bs[1], n0, 0, 1); STG(Bt, Bs[1], n0, 1, 1);
  asm volatile("s_waitcnt vmcnt(4)" ::: "memory");
  BAR();

  for (int kt = 0; kt < 32; ++kt) {
    const int par = kt & 1;
    const u16* Asp = As[par];
    const u16* Bsp = Bs[par];
    u16* Asn = As[par ^ 1];
    u16* Bsn = Bs[par];               // B(kt+2) has same parity as B(kt)
    bf16x8_t bfr[4][2], af[2][2];

    if constexpr (MODE == 0) {
#pragma unroll
      for (int n = 0; n < 4; ++n) {
        bfr[n][0] = *reinterpret_cast<const bf16x8_t*>(Bsp + rowxB + n * 1024 + cof0);
        bfr[n][1] = *reinterpret_cast<const bf16x8_t*>(Bsp + rowxB + n * 1024 + cof1);
      }
      LDAF(0);
      if (kt + 1 < 32) { STG(A, Asn, m0, 0, kt + 1); STG(A, Asn, m0, 1, kt + 1); }
      BAR();
      __builtin_amdgcn_s_setprio(1);
      MFMA8(0);
      __builtin_amdgcn_s_setprio(0);
      BAR();

      LDAF(2);
      if (kt + 2 < 32) { STG(Bt, Bsn, n0, 0, kt + 2); }
      BAR();
      __builtin_amdgcn_s_setprio(1);
      MFMA8(2);
      __builtin_amdgcn_s_setprio(0);
      BAR();

      LDAF(4);
      if (kt + 2 < 32) { STG(Bt, Bsn, n0, 1, kt + 2); }
      BAR();
      __builtin_amdgcn_s_setprio(1);
      MFMA8(4);
      __builtin_amdgcn_s_setprio(0);
      BAR();

      LDAF(6);
      BAR();
      __builtin_amdgcn_s_setprio(1);
      MFMA8(6);
      __builtin_amdgcn_s_setprio(0);
      if (kt + 2 < 32) { asm volatile("s_waitcnt vmcnt(4)" ::: "memory"); }
      else             { asm volatile("s_waitcnt vmcnt(0)" ::: "memory"); }
      BAR();
    } else {
#pragma unroll
      for (int n = 0; n < 4; ++n) {
        bfr[n][0] = *reinterpret_cast<const bf16x8_t*>(Bsp + rowxB + n * 1024 + cof0);
        bfr[n][1] = *reinterpret_cast<const bf16x8_t*>(Bsp + rowxB + n * 1024 + cof1);
      }
      LDAF(0);
      if (kt + 1 < 32) { STG(A, Asn, m0, 0, kt + 1); }
      BAR();
      __builtin_amdgcn_s_setprio(1);
      MFMA8(0);
      __builtin_amdgcn_s_setprio(0);
      BAR();

      LDAF(2);
      if (kt + 2 < 32) { STG(Bt, Bsn, n0, 0, kt + 2); STG(Bt, Bsn, n0, 1, kt + 2); }
      BAR();
      __builtin_amdgcn_s_setprio(1);
      MFMA8(2);
      __builtin_amdgcn_s_setprio(0);
      if (kt + 2 < 32) { asm volatile("s_waitcnt vmcnt(4)" ::: "memory"); }
      else             { asm volatile("s_waitcnt vmcnt(0)" ::: "memory"); }
      BAR();
    }
  }

  if constexpr (MODE == 0) {
    const int colbase = n0 + wc * 64;   // multiple of 64 -> one head per wave
    if (n0 < 2048) {
      const int hq = colbase >> 6;
#pragma unroll
      for (int i = 0; i < MF; i++) {
        int rw0 = m0 + wr * (BMx / 2) + i * 16 + quad * 4;
#pragma unroll
        for (int j = 0; j < 2; j++) {
          int d = j * 16 + ln;     // < 32
          float b0 = bq[colbase + d];
          float b1 = bq[colbase + d + 32];
#pragma unroll
          for (int r = 0; r < 4; r++) {
            int row = rw0 + r;
            float c  = cosb[row * 32 + d];
            float sn = sinb[row * 32 + d];
            float v0 = acc[i][j][r]     + b0;
            float v1 = acc[i][j + 2][r] + b1;
            int bb = row >> 11, s = row & (S_ - 1);
            size_t base = ((size_t)(bb * NH_ + hq) * S_ + s) * HD_;
            Qb[base + d]      = f2bf((v0 * c - v1 * sn) * 0.125f);
            Qb[base + d + 32] = f2bf((v1 * c + v0 * sn) * 0.125f);
          }
        }
      }
    } else if (n0 < 2560) {
      const int kh = (colbase - 2048) >> 6;
#pragma unroll
      for (int i = 0; i < MF; i++) {
        int rw0 = m0 + wr * (BMx / 2) + i * 16 + quad * 4;
#pragma unroll
        for (int j = 0; j < 2; j++) {
          int d = j * 16 + ln;
          float b0 = bk[(colbase - 2048) + d];
          float b1 = bk[(colbase - 2048) + d + 32];
#pragma unroll
          for (int r = 0; r < 4; r++) {
            int row = rw0 + r;
            float c  = cosb[row * 32 + d];
            float sn = sinb[row * 32 + d];
            float v0 = acc[i][j][r]     + b0;
            float v1 = acc[i][j + 2][r] + b1;
            int bb = row >> 11, s = row & (S_ - 1);
            size_t base = ((size_t)(bb * NKV_ + kh) * S_ + s) * HD_;
            Kb[base + d]      = f2bf(v0 * c - v1 * sn);
            Kb[base + d + 32] = f2bf(v1 * c + v0 * sn);
          }
        }
      }
    } else {
#pragma unroll
      for (int i = 0; i < MF; i++) {
        int rw0 = m0 + wr * (BMx / 2) + i * 16 + quad * 4;
#pragma unroll
        for (int j = 0; j < 4; j++) {
          int cv = colbase - 2560 + j * 16 + ln;
          float bvv = bv[cv];
#pragma unroll
          for (int r = 0; r < 4; r++)
            Vtmp[(size_t)(rw0 + r) * 512 + cv] = f2bf(acc[i][j][r] + bvv);
        }
      }
    }
  } else {
#pragma unroll
    for (int i = 0; i < MF; i++) {
      int row = m0 + wr * (BMx / 2) + i * 16 + quad * 4;
#pragma unroll
      for (int j = 0; j < 4; j++) {
        int col = n0 + wc * 64 + j * 16 + ln;
        float* cp = Cout + (size_t)row * Nout + col;
#pragma unroll
        for (int r = 0; r < 4; r++)
          cp[(size_t)r * Nout] = acc[i][j][r];
      }
    }
  }
}

// V^T with kv-permuted columns from bf16 Vtmp [4096][512].
__global__ void prep_v(const u16* __restrict__ Vtmp, u16* __restrict__ Vt) {
  __shared__ u16 tile[64][65];
  const int sb  = blockIdx.x * 64;
  const int bk  = blockIdx.y;
  const int b   = bk >> 3, kvh = bk & 7;
  const int tx  = threadIdx.x & 63;
  const int ty  = threadIdx.x >> 6;   // 0..3
  const u16* src = Vtmp + (size_t)(b * 2048 + sb) * 512 + kvh * 64;
#pragma unroll
  for (int i = ty; i < 64; i += 4)
    tile[i][tx] = src[(size_t)i * 512 + tx];
  __syncthreads();
  const int sp = sb + (tx & 15) * 4 + (tx >> 4);   // permuted col
  u16* dst = Vt + (size_t)(b * NKV_ + kvh) * HD_ * (size_t)S_;
#pragma unroll
  for (int j = ty; j < 64; j += 4)
    dst[(size_t)j * S_ + sp] = tile[tx][j];
}

// ---------------- causal GQA flash attention ----------------
// v7 (reverted from v8 merged-tile, which spilled past the 128-VGPR cap of
// launch_bounds(256,2) and regressed ~25us): 3-buffer K/V ring, prefetch 2
// steps ahead, counted vmcnt(4) + raw s_barrier (T3/T4).
__global__ __launch_bounds__(256, 2) void flash_attn(
    const u16* __restrict__ Qb, const u16* __restrict__ Kb, const u16* __restrict__ Vt,
    u16* __restrict__ Og) {
  const int u    = blockIdx.x;        // 0..31
  const int bk   = blockIdx.y;
  const int b    = bk >> 3;
  const int kvh  = bk & 7;
  const int tid  = threadIdx.x;
  const int wv   = tid >> 6;
  const int h    = kvh * 4 + wv;
  const int lane = tid & 63;
  const int ln   = lane & 15;
  const int quad = lane >> 4;

  __shared__ __align__(16) u16 Kl[3][64 * 64];
  __shared__ __align__(16) u16 Vl[3][64 * 64];
  __shared__ __align__(16) u16 Plds[4][2][16][72];

  const u16* Qbase = Qb + ((size_t)(b * NH_ + h) * S_) * HD_;
  const u16* Kbase = Kb + ((size_t)(b * NKV_ + kvh) * S_) * HD_;
  const u16* Vbase = Vt + ((size_t)(b * NKV_ + kvh) * HD_) * S_;

  const int j0 = wv * 2, j1 = wv * 2 + 1;
  const int p0 = j0 * 64 + lane,  p1 = j1 * 64 + lane;
  const int r0 = p0 >> 3,  c0 = (p0 & 7) ^ (r0 & 7);
  const int r1 = p1 >> 3,  c1 = (p1 & 7) ^ (r1 & 7);

  const int sw  = ln & 7;
  const int ck0 = quad ^ sw;
  const int ck1 = ck0 ^ 4;

  const int tlist[2] = {u, 63 - u};

  for (int ti = 0; ti < 2; ++ti) {
    const int t = tlist[ti];
    const int qrow0 = t * 32;
    const int nsteps = t / 2 + 1;

    bf16x8_t qf[2][2];
#pragma unroll
    for (int mt = 0; mt < 2; mt++) {
      qf[mt][0] = *reinterpret_cast<const bf16x8_t*>(
          Qbase + (size_t)(qrow0 + mt * 16 + ln) * HD_ + quad * 8);
      qf[mt][1] = *reinterpret_cast<const bf16x8_t*>(
          Qbase + (size_t)(qrow0 + mt * 16 + ln) * HD_ + 32 + quad * 8);
    }

    f32x4_t O[2][4];
#pragma unroll
    for (int mt = 0; mt < 2; mt++)
#pragma unroll
      for (int dt = 0; dt < 4; dt++)
        O[mt][dt] = (f32x4_t){0.f, 0.f, 0.f, 0.f};
    float l[2][4];
#pragma unroll
    for (int mt = 0; mt < 2; mt++)
#pragma unroll
      for (int r = 0; r < 4; r++) l[mt][r] = 0.f;

    __syncthreads();   // prev-ti readers done; full vmcnt drain (incl. O stores)

    // stage steps 0 and 1 into bufs 0 and 1 (step-1 addresses always in-bounds)
    gload16(Kbase + (size_t)r0 * HD_ + c0 * 8,        &Kl[0][j0 * 512]);
    gload16(Kbase + (size_t)r1 * HD_ + c1 * 8,        &Kl[0][j1 * 512]);
    gload16(Vbase + (size_t)r0 * S_ + c0 * 8,         &Vl[0][j0 * 512]);
    gload16(Vbase + (size_t)r1 * S_ + c1 * 8,         &Vl[0][j1 * 512]);
    gload16(Kbase + (size_t)(64 + r0) * HD_ + c0 * 8, &Kl[1][j0 * 512]);
    gload16(Kbase + (size_t)(64 + r1) * HD_ + c1 * 8, &Kl[1][j1 * 512]);
    gload16(Vbase + (size_t)r0 * S_ + 64 + c0 * 8,    &Vl[1][j0 * 512]);
    gload16(Vbase + (size_t)r1 * S_ + 64 + c1 * 8,    &Vl[1][j1 * 512]);

    for (int step = 0; step < nsteps; ++step) {
      const int cur = step % 3;
      const int kv0 = step * 64;
      // counted wait: 4 gloads/stage; with stage(step+1) in flight, waiting
      // to 4 completes exactly stage(step). Tail drains to 0.
      if (step + 1 < nsteps) { asm volatile("s_waitcnt vmcnt(4)" ::: "memory"); }
      else                   { asm volatile("s_waitcnt vmcnt(0)" ::: "memory"); }
      __builtin_amdgcn_s_barrier();
      __builtin_amdgcn_sched_barrier(0);

      if (step + 2 < nsteps) {
        const int nb  = (step + 2) % 3;
        const int nkv = kv0 + 128;
        gload16(Kbase + (size_t)(nkv + r0) * HD_ + c0 * 8, &Kl[nb][j0 * 512]);
        gload16(Kbase + (size_t)(nkv + r1) * HD_ + c1 * 8, &Kl[nb][j1 * 512]);
        gload16(Vbase + (size_t)r0 * S_ + nkv + c0 * 8,    &Vl[nb][j0 * 512]);
        gload16(Vbase + (size_t)r1 * S_ + nkv + c1 * 8,    &Vl[nb][j1 * 512]);
      }

      const u16* Kc = Kl[cur];
      const u16* Vc = Vl[cur];

      bf16x8_t kf0[4], kf1[4];
#pragma unroll
      for (int kt = 0; kt < 4; kt++) {
        const u16* rp = Kc + (kt * 16 + ln) * 64;
        kf0[kt] = *reinterpret_cast<const bf16x8_t*>(rp + ck0 * 8);
        kf1[kt] = *reinterpret_cast<const bf16x8_t*>(rp + ck1 * 8);
      }
      f32x4_t s[2][4];
#pragma unroll
      for (int mt = 0; mt < 2; mt++)
#pragma unroll
        for (int kt = 0; kt < 4; kt++) {
          f32x4_t acc = (f32x4_t){0.f, 0.f, 0.f, 0.f};
          acc = __builtin_amdgcn_mfma_f32_16x16x32_bf16(qf[mt][0], kf0[kt], acc, 0, 0, 0);
          acc = __builtin_amdgcn_mfma_f32_16x16x32_bf16(qf[mt][1], kf1[kt], acc, 0, 0, 0);
          s[mt][kt] = acc;
        }

      bf16x8_t vf0[4], vf1[4];
#pragma unroll
      for (int dt = 0; dt < 4; dt++) {
        const u16* rp = Vc + (dt * 16 + ln) * 64;
        vf0[dt] = *reinterpret_cast<const bf16x8_t*>(rp + ck0 * 8);
        vf1[dt] = *reinterpret_cast<const bf16x8_t*>(rp + ck1 * 8);
      }

      if (kv0 + 63 > qrow0) {
#pragma unroll
        for (int mt = 0; mt < 2; mt++)
#pragma unroll
          for (int kt = 0; kt < 4; kt++)
#pragma unroll
            for (int r = 0; r < 4; r++) {
              int rowg = qrow0 + mt * 16 + quad * 4 + r;
              if (kv0 + kt * 16 + ln > rowg) s[mt][kt][r] = -1e30f;
            }
      }

#pragma unroll
      for (int mt = 0; mt < 2; mt++)
#pragma unroll
        for (int r = 0; r < 4; r++) {
          float p0f = __expf(s[mt][0][r] - MEXP);
          float p1f = __expf(s[mt][1][r] - MEXP);
          float p2f = __expf(s[mt][2][r] - MEXP);
          float p3f = __expf(s[mt][3][r] - MEXP);
          l[mt][r] += (p0f + p1f) + (p2f + p3f);
          ushort4 pk;   // truncation pack (bias cancels in O/l)
          pk.x = (u16)(__float_as_uint(p0f) >> 16);
          pk.y = (u16)(__float_as_uint(p1f) >> 16);
          pk.z = (u16)(__float_as_uint(p2f) >> 16);
          pk.w = (u16)(__float_as_uint(p3f) >> 16);
          *reinterpret_cast<ushort4*>(&Plds[wv][mt][quad * 4 + r][ln * 4]) = pk;
        }

#pragma unroll
      for (int mt = 0; mt < 2; mt++) {
        bf16x8_t pf0 = *reinterpret_cast<const bf16x8_t*>(&Plds[wv][mt][ln][quad * 8]);
        bf16x8_t pf1 = *reinterpret_cast<const bf16x8_t*>(&Plds[wv][mt][ln][32 + quad * 8]);
#pragma unroll
        for (int dt = 0; dt < 4; dt++) {
          O[mt][dt] = __builtin_amdgcn_mfma_f32_16x16x32_bf16(pf0, vf0[dt], O[mt][dt], 0, 0, 0);
          O[mt][dt] = __builtin_amdgcn_mfma_f32_16x16x32_bf16(pf1, vf1[dt], O[mt][dt], 0, 0, 0);
        }
      }
    }

#pragma unroll
    for (int mt = 0; mt < 2; mt++)
#pragma unroll
      for (int r = 0; r < 4; r++) {
        float lv = l[mt][r];
        lv += __shfl_xor(lv, 1);
        lv += __shfl_xor(lv, 2);
        lv += __shfl_xor(lv, 4);
        lv += __shfl_xor(lv, 8);
        float inv = 1.0f / lv;
        int srow = qrow0 + mt * 16 + quad * 4 + r;
        size_t base = ((size_t)b * S_ + srow) * (size_t)(NH_ * HD_) + h * HD_;
#pragma unroll
        for (int dt = 0; dt < 4; dt++)
          Og[base + dt * 16 + ln] = f2bf(O[mt][dt][r] * inv);
      }
  }
}

// ---------------- launch ----------------

extern "C" void kernel_launch(void* const* d_in, const int* in_sizes, int n_in,
                              void* d_out, int out_size, void* d_ws, size_t ws_size,
                              hipStream_t stream) {
  const float* x  = (const float*)d_in[0];
  const int*   pos = (const int*)d_in[1];
  const float* Wq = (const float*)d_in[2];
  const float* bq = (const float*)d_in[3];
  const float* Wk = (const float*)d_in[4];
  const float* bk = (const float*)d_in[5];
  const float* Wv = (const float*)d_in[6];
  const float* bv = (const float*)d_in[7];
  const float* Wo = (const float*)d_in[8];
  float* out = (float*)d_out;

  char* ws = (char*)d_ws;
  u16*   xb    = (u16*)(ws);                     // [4096][2048] bf16   16.8MB
  u16*   Wqkvt = (u16*)(ws + 16777216);          // [3072][2048] bf16   12.6MB
  u16*   Wot   = (u16*)(ws + 29360128);          // [2048][2048] bf16    8.4MB
  float* cosb  = (float*)(ws + 37748736);        // [4096][32] f32
  float* sinb  = (float*)(ws + 38797312);        // [4096][32] f32
  u16*   Qb    = (u16*)(ws + 39845888);          // [B][NH][S][HD]      16.8MB
  u16*   Kb    = (u16*)(ws + 56623104);          // [B][NKV][S][HD]      4.2MB
  u16*   Vtmp  = (u16*)(ws + 60817408);          // [4096][512] bf16     4.2MB
  u16*   Vt    = (u16*)(ws + 65011712);          // [B][NKV][HD][S]      4.2MB (kv-permuted)
  u16*   Og    = (u16*)(ws + 69206016);          // [4096][2048] bf16   16.8MB

  prep_all<<<18944, 256, 0, stream>>>(x, xb, Wq, Wk, Wv, Wqkvt, Wo, Wot,
                                      pos, cosb, sinb);

  gemm256<0><<<dim3(16, 12), 512, 0, stream>>>(xb, Wqkvt, bq, bk, bv, cosb, sinb,
                                               Qb, Kb, Vtmp, nullptr, 0);

  prep_v<<<dim3(32, 16), 256, 0, stream>>>(Vtmp, Vt);

  flash_attn<<<dim3(32, 16), 256, 0, stream>>>(Qb, Kb, Vt, Og);

  gemm256<1><<<dim3(32, 8), 512, 0, stream>>>(Og, Wot, nullptr, nullptr, nullptr,
                                              nullptr, nullptr, nullptr, nullptr, nullptr,
                                              out, 2048);
}

// Round 8
// 288.297 us; speedup vs baseline: 1.1375x; 1.0380x over previous
//
#include <hip/hip_runtime.h>

#define B_   2
#define S_   2048
#define H_   2048
#define NH_  32
#define NKV_ 8
#define HD_  64
#define ROWS (B_*S_)   // 4096
#define MEXP 20.0f

typedef unsigned short u16;
typedef __bf16 bf16x8_t __attribute__((ext_vector_type(8)));
typedef float  f32x4_t  __attribute__((ext_vector_type(4)));

__device__ __forceinline__ u16 f2bf(float f) {
  union { float f; unsigned u; } v; v.f = f;
  unsigned u = v.u;
  u += 0x7FFFu + ((u >> 16) & 1u);
  return (u16)(u >> 16);
}

// async global->LDS, 16B per lane. LDS dest = wave-uniform base + lane*16.
__device__ __forceinline__ void gload16(const u16* g, u16* l) {
  __builtin_amdgcn_global_load_lds((const __attribute__((address_space(1))) void*)g,
                                   (__attribute__((address_space(3))) void*)l, 16, 0, 0);
}

// ---------------- fused input prep: cvt | transpose_wqkv | transpose_w | cossin ----------------
__global__ void prep_all(const float* __restrict__ x, u16* __restrict__ xb,
                         const float* __restrict__ Wq, const float* __restrict__ Wk,
                         const float* __restrict__ Wv, u16* __restrict__ Wqkvt,
                         const float* __restrict__ Wo, u16* __restrict__ Wot,
                         const int* __restrict__ pos,
                         float* __restrict__ cosb, float* __restrict__ sinb) {
  __shared__ float t[32][33];
  int bid = blockIdx.x;
  if (bid < 8192) {
    int i = bid * 256 + threadIdx.x;
    float4 v = reinterpret_cast<const float4*>(x)[i];
    ushort4 o;
    o.x = f2bf(v.x); o.y = f2bf(v.y); o.z = f2bf(v.z); o.w = f2bf(v.w);
    reinterpret_cast<ushort4*>(xb)[i] = o;
    return;
  }
  bid -= 8192;
  const int tx = threadIdx.x & 31, ty = threadIdx.x >> 5;   // (32,8)
  if (bid < 6144) {
    const int bx = bid % 96, by = bid / 96;
    const int k0  = by * 32;
    const int n0g = bx * 32;
    const float* src; int N, n0;
    if (n0g < 2048)      { src = Wq; N = 2048; n0 = n0g; }
    else if (n0g < 2560) { src = Wk; N = 512;  n0 = n0g - 2048; }
    else                 { src = Wv; N = 512;  n0 = n0g - 2560; }
#pragma unroll
    for (int i = 0; i < 32; i += 8)
      t[ty + i][tx] = src[(size_t)(k0 + ty + i) * N + n0 + tx];
    __syncthreads();
#pragma unroll
    for (int i = 0; i < 32; i += 8)
      Wqkvt[(size_t)(n0g + ty + i) * 2048 + k0 + tx] = f2bf(t[tx][ty + i]);
    return;
  }
  bid -= 6144;
  if (bid < 4096) {
    const int bx = bid % 64, by = bid / 64;
    const int k0 = by * 32;
    const int n0 = bx * 32;
#pragma unroll
    for (int i = 0; i < 32; i += 8)
      t[ty + i][tx] = Wo[(size_t)(k0 + ty + i) * 2048 + n0 + tx];
    __syncthreads();
#pragma unroll
    for (int i = 0; i < 32; i += 8)
      Wot[(size_t)(n0 + ty + i) * 2048 + k0 + tx] = f2bf(t[tx][ty + i]);
    return;
  }
  bid -= 4096;
  {
    int tt = bid * 256 + threadIdx.x;   // row*32 + d
    int row = tt >> 5, d = tt & 31;
    int sec = (d < 16) ? 0 : 1;
    float p = (float)pos[sec * ROWS + row];
    float inv_freq = powf(1.0e6f, -(float)d * (1.0f / 32.0f));
    float fr = p * inv_freq;
    float s, c;
    sincosf(fr, &s, &c);
    cosb[tt] = c;
    sinb[tt] = s;
  }
}

// ---------------- BK=64 merged-phase pipelined GEMM (T2+T3+T4+T5) ----------------
// R7: barrier count halved. MODE 0: 2 phases/K-tile (was 4), 8->4 barriers.
// MODE 1: 3 barriers/K-tile (was 4). Safety invariant: B(kt+2) staging is
// issued only after a barrier that follows all waves' bfr-consuming MFMAs.
// vmcnt ring (MODE0): entering kt queue=[B(kt+1)x4]; P0 issues A(kt+1)x4,
// P1 issues B(kt+2)x4; vmcnt(4) retires B(kt+1)+A(kt+1). Tail drains to 0.

#define BAR() { __builtin_amdgcn_s_barrier(); __builtin_amdgcn_sched_barrier(0); }

#define STG(G, L, RB, h, kt) { \
    const u16* g_ = (G) + (size_t)((RB) + (h) * 128 + srow) * 2048 + (kt) * 64 + sc8; \
    gload16(g_,             (L) + (h) * 8192 + sldo);       \
    gload16(g_ + 8 * 2048,  (L) + (h) * 8192 + sldo + 512); }

#define LDAF(mm) \
    af[0][0] = *reinterpret_cast<const bf16x8_t*>(Asp + rowxA + (mm) * 1024 + cof0); \
    af[0][1] = *reinterpret_cast<const bf16x8_t*>(Asp + rowxA + (mm) * 1024 + cof1); \
    af[1][0] = *reinterpret_cast<const bf16x8_t*>(Asp + rowxA + (mm) * 1024 + 1024 + cof0); \
    af[1][1] = *reinterpret_cast<const bf16x8_t*>(Asp + rowxA + (mm) * 1024 + 1024 + cof1);

#define MFMA8(mb) \
    _Pragma("unroll") \
    for (int n = 0; n < 4; ++n) { \
      acc[(mb)][n]     = __builtin_amdgcn_mfma_f32_16x16x32_bf16(af[0][0], bfr[n][0], acc[(mb)][n], 0, 0, 0); \
      acc[(mb)][n]     = __builtin_amdgcn_mfma_f32_16x16x32_bf16(af[0][1], bfr[n][1], acc[(mb)][n], 0, 0, 0); \
      acc[(mb) + 1][n] = __builtin_amdgcn_mfma_f32_16x16x32_bf16(af[1][0], bfr[n][0], acc[(mb) + 1][n], 0, 0, 0); \
      acc[(mb) + 1][n] = __builtin_amdgcn_mfma_f32_16x16x32_bf16(af[1][1], bfr[n][1], acc[(mb) + 1][n], 0, 0, 0); \
    }

template <int MODE>
__global__ __launch_bounds__(512, 2) void gemm256(
    const u16* __restrict__ A, const u16* __restrict__ Bt,
    const float* __restrict__ bq, const float* __restrict__ bk, const float* __restrict__ bv,
    const float* __restrict__ cosb, const float* __restrict__ sinb,
    u16* __restrict__ Qb, u16* __restrict__ Kb, u16* __restrict__ Vtmp,
    float* __restrict__ Cout, int Nout) {
  constexpr int BMx = (MODE == 0) ? 256 : 128;   // M tile
  constexpr int MF  = BMx / 32;                  // per-wave m-frags (8 or 4)

  const int m0 = blockIdx.x * BMx;
  const int n0 = blockIdx.y * 256;

  __shared__ __align__(16) u16 As[2][BMx * 64];
  __shared__ __align__(16) u16 Bs[2][16384];
  const int tid  = threadIdx.x;
  const int lane = tid & 63;
  const int wv   = tid >> 6;        // 0..7
  const int wr   = wv >> 2;         // 0..1  (M half)
  const int wc   = wv & 3;          // 0..3  (N quarter)
  const int ln   = lane & 15;
  const int quad = lane >> 4;

  const int srow = wv * 16 + (lane >> 3);            // row within half (2nd gload +8)
  const int sc8  = ((lane & 7) ^ (lane >> 3)) * 8;   // pre-swizzled k-chunk (u16)
  const int sldo = wv * 1024;                        // u16 offset of wave slice

  const int rowxA = (wr * (BMx / 2) + ln) * 64;
  const int rowxB = (wc * 64       + ln) * 64;
  const int cof0  = ((quad    ) ^ (ln & 7)) * 8;     // kk=0 chunk = quad
  const int cof1  = ((quad ^ 4) ^ (ln & 7)) * 8;     // kk=1 chunk = 4+quad

  f32x4_t acc[MF][4];
#pragma unroll
  for (int i = 0; i < MF; i++)
#pragma unroll
    for (int j = 0; j < 4; j++)
      acc[i][j] = (f32x4_t){0.f, 0.f, 0.f, 0.f};

  STG(A, As[0], m0, 0, 0);
  if constexpr (MODE == 0) { STG(A, As[0], m0, 1, 0); }
  STG(Bt, Bs[0], n0, 0, 0); STG(Bt, Bs[0], n0, 1, 0);
  STG(Bt, Bs[1], n0, 0, 1); STG(Bt, Bs[1], n0, 1, 1);
  asm volatile("s_waitcnt vmcnt(4)" ::: "memory");
  BAR();

  for (int kt = 0; kt < 32; ++kt) {
    const int par = kt & 1;
    const u16* Asp = As[par];
    const u16* Bsp = Bs[par];
    u16* Asn = As[par ^ 1];
    u16* Bsn = Bs[par];               // B(kt+2) has same parity as B(kt)
    bf16x8_t bfr[4][2], af[2][2];

    if constexpr (MODE == 0) {
      // ---- merged phase P0: B frags + A(m0..m3); stage A(kt+1) both halves ----
#pragma unroll
      for (int n = 0; n < 4; ++n) {
        bfr[n][0] = *reinterpret_cast<const bf16x8_t*>(Bsp + rowxB + n * 1024 + cof0);
        bfr[n][1] = *reinterpret_cast<const bf16x8_t*>(Bsp + rowxB + n * 1024 + cof1);
      }
      LDAF(0);
      if (kt + 1 < 32) { STG(A, Asn, m0, 0, kt + 1); STG(A, Asn, m0, 1, kt + 1); }
      BAR();
      __builtin_amdgcn_s_setprio(1);
      MFMA8(0);
      __builtin_amdgcn_s_setprio(0);
      LDAF(2);
      __builtin_amdgcn_s_setprio(1);
      MFMA8(2);
      __builtin_amdgcn_s_setprio(0);
      BAR();   // all waves consumed bfr -> B(kt+2) staging below is safe

      // ---- merged phase P1: A(m4..m7); stage B(kt+2); counted vmcnt ----
      LDAF(4);
      if (kt + 2 < 32) { STG(Bt, Bsn, n0, 0, kt + 2); STG(Bt, Bsn, n0, 1, kt + 2); }
      BAR();
      __builtin_amdgcn_s_setprio(1);
      MFMA8(4);
      __builtin_amdgcn_s_setprio(0);
      LDAF(6);
      __builtin_amdgcn_s_setprio(1);
      MFMA8(6);
      __builtin_amdgcn_s_setprio(0);
      if (kt + 2 < 32) { asm volatile("s_waitcnt vmcnt(4)" ::: "memory"); }
      else             { asm volatile("s_waitcnt vmcnt(0)" ::: "memory"); }
      BAR();
    } else {
      // ---- P0: B frags + A(m0,m1); stage A(kt+1) ----
#pragma unroll
      for (int n = 0; n < 4; ++n) {
        bfr[n][0] = *reinterpret_cast<const bf16x8_t*>(Bsp + rowxB + n * 1024 + cof0);
        bfr[n][1] = *reinterpret_cast<const bf16x8_t*>(Bsp + rowxB + n * 1024 + cof1);
      }
      LDAF(0);
      if (kt + 1 < 32) { STG(A, Asn, m0, 0, kt + 1); }
      BAR();
      __builtin_amdgcn_s_setprio(1);
      MFMA8(0);
      __builtin_amdgcn_s_setprio(0);
      BAR();   // bfr consumed by all -> B(kt+2) staging safe

      // ---- P1: A(m2,m3); stage B(kt+2); counted vmcnt ----
      LDAF(2);
      if (kt + 2 < 32) { STG(Bt, Bsn, n0, 0, kt + 2); STG(Bt, Bsn, n0, 1, kt + 2); }
      __builtin_amdgcn_s_setprio(1);
      MFMA8(2);
      __builtin_amdgcn_s_setprio(0);
      if (kt + 2 < 32) { asm volatile("s_waitcnt vmcnt(4)" ::: "memory"); }
      else             { asm volatile("s_waitcnt vmcnt(0)" ::: "memory"); }
      BAR();
    }
  }

  if constexpr (MODE == 0) {
    const int colbase = n0 + wc * 64;   // multiple of 64 -> one head per wave
    if (n0 < 2048) {
      const int hq = colbase >> 6;
#pragma unroll
      for (int i = 0; i < MF; i++) {
        int rw0 = m0 + wr * (BMx / 2) + i * 16 + quad * 4;
#pragma unroll
        for (int j = 0; j < 2; j++) {
          int d = j * 16 + ln;     // < 32
          float b0 = bq[colbase + d];
          float b1 = bq[colbase + d + 32];
#pragma unroll
          for (int r = 0; r < 4; r++) {
            int row = rw0 + r;
            float c  = cosb[row * 32 + d];
            float sn = sinb[row * 32 + d];
            float v0 = acc[i][j][r]     + b0;
            float v1 = acc[i][j + 2][r] + b1;
            int bb = row >> 11, s = row & (S_ - 1);
            size_t base = ((size_t)(bb * NH_ + hq) * S_ + s) * HD_;
            Qb[base + d]      = f2bf((v0 * c - v1 * sn) * 0.125f);
            Qb[base + d + 32] = f2bf((v1 * c + v0 * sn) * 0.125f);
          }
        }
      }
    } else if (n0 < 2560) {
      const int kh = (colbase - 2048) >> 6;
#pragma unroll
      for (int i = 0; i < MF; i++) {
        int rw0 = m0 + wr * (BMx / 2) + i * 16 + quad * 4;
#pragma unroll
        for (int j = 0; j < 2; j++) {
          int d = j * 16 + ln;
          float b0 = bk[(colbase - 2048) + d];
          float b1 = bk[(colbase - 2048) + d + 32];
#pragma unroll
          for (int r = 0; r < 4; r++) {
            int row = rw0 + r;
            float c  = cosb[row * 32 + d];
            float sn = sinb[row * 32 + d];
            float v0 = acc[i][j][r]     + b0;
            float v1 = acc[i][j + 2][r] + b1;
            int bb = row >> 11, s = row & (S_ - 1);
            size_t base = ((size_t)(bb * NKV_ + kh) * S_ + s) * HD_;
            Kb[base + d]      = f2bf(v0 * c - v1 * sn);
            Kb[base + d + 32] = f2bf(v1 * c + v0 * sn);
          }
        }
      }
    } else {
#pragma unroll
      for (int i = 0; i < MF; i++) {
        int rw0 = m0 + wr * (BMx / 2) + i * 16 + quad * 4;
#pragma unroll
        for (int j = 0; j < 4; j++) {
          int cv = colbase - 2560 + j * 16 + ln;
          float bvv = bv[cv];
#pragma unroll
          for (int r = 0; r < 4; r++)
            Vtmp[(size_t)(rw0 + r) * 512 + cv] = f2bf(acc[i][j][r] + bvv);
        }
      }
    }
  } else {
#pragma unroll
    for (int i = 0; i < MF; i++) {
      int row = m0 + wr * (BMx / 2) + i * 16 + quad * 4;
#pragma unroll
      for (int j = 0; j < 4; j++) {
        int col = n0 + wc * 64 + j * 16 + ln;
        float* cp = Cout + (size_t)row * Nout + col;
#pragma unroll
        for (int r = 0; r < 4; r++)
          cp[(size_t)r * Nout] = acc[i][j][r];
      }
    }
  }
}

// V^T with kv-permuted columns from bf16 Vtmp [4096][512].
__global__ void prep_v(const u16* __restrict__ Vtmp, u16* __restrict__ Vt) {
  __shared__ u16 tile[64][65];
  const int sb  = blockIdx.x * 64;
  const int bk  = blockIdx.y;
  const int b   = bk >> 3, kvh = bk & 7;
  const int tx  = threadIdx.x & 63;
  const int ty  = threadIdx.x >> 6;   // 0..3
  const u16* src = Vtmp + (size_t)(b * 2048 + sb) * 512 + kvh * 64;
#pragma unroll
  for (int i = ty; i < 64; i += 4)
    tile[i][tx] = src[(size_t)i * 512 + tx];
  __syncthreads();
  const int sp = sb + (tx & 15) * 4 + (tx >> 4);   // permuted col
  u16* dst = Vt + (size_t)(b * NKV_ + kvh) * HD_ * (size_t)S_;
#pragma unroll
  for (int j = ty; j < 64; j += 4)
    dst[(size_t)j * S_ + sp] = tile[tx][j];
}

// ---------------- causal GQA flash attention (v7) ----------------
__global__ __launch_bounds__(256, 2) void flash_attn(
    const u16* __restrict__ Qb, const u16* __restrict__ Kb, const u16* __restrict__ Vt,
    u16* __restrict__ Og) {
  const int u    = blockIdx.x;        // 0..31
  const int bk   = blockIdx.y;
  const int b    = bk >> 3;
  const int kvh  = bk & 7;
  const int tid  = threadIdx.x;
  const int wv   = tid >> 6;
  const int h    = kvh * 4 + wv;
  const int lane = tid & 63;
  const int ln   = lane & 15;
  const int quad = lane >> 4;

  __shared__ __align__(16) u16 Kl[3][64 * 64];
  __shared__ __align__(16) u16 Vl[3][64 * 64];
  __shared__ __align__(16) u16 Plds[4][2][16][72];

  const u16* Qbase = Qb + ((size_t)(b * NH_ + h) * S_) * HD_;
  const u16* Kbase = Kb + ((size_t)(b * NKV_ + kvh) * S_) * HD_;
  const u16* Vbase = Vt + ((size_t)(b * NKV_ + kvh) * HD_) * S_;

  const int j0 = wv * 2, j1 = wv * 2 + 1;
  const int p0 = j0 * 64 + lane,  p1 = j1 * 64 + lane;
  const int r0 = p0 >> 3,  c0 = (p0 & 7) ^ (r0 & 7);
  const int r1 = p1 >> 3,  c1 = (p1 & 7) ^ (r1 & 7);

  const int sw  = ln & 7;
  const int ck0 = quad ^ sw;
  const int ck1 = ck0 ^ 4;

  const int tlist[2] = {u, 63 - u};

  for (int ti = 0; ti < 2; ++ti) {
    const int t = tlist[ti];
    const int qrow0 = t * 32;
    const int nsteps = t / 2 + 1;

    bf16x8_t qf[2][2];
#pragma unroll
    for (int mt = 0; mt < 2; mt++) {
      qf[mt][0] = *reinterpret_cast<const bf16x8_t*>(
          Qbase + (size_t)(qrow0 + mt * 16 + ln) * HD_ + quad * 8);
      qf[mt][1] = *reinterpret_cast<const bf16x8_t*>(
          Qbase + (size_t)(qrow0 + mt * 16 + ln) * HD_ + 32 + quad * 8);
    }

    f32x4_t O[2][4];
#pragma unroll
    for (int mt = 0; mt < 2; mt++)
#pragma unroll
      for (int dt = 0; dt < 4; dt++)
        O[mt][dt] = (f32x4_t){0.f, 0.f, 0.f, 0.f};
    float l[2][4];
#pragma unroll
    for (int mt = 0; mt < 2; mt++)
#pragma unroll
      for (int r = 0; r < 4; r++) l[mt][r] = 0.f;

    __syncthreads();   // prev-ti readers done; full vmcnt drain (incl. O stores)

    gload16(Kbase + (size_t)r0 * HD_ + c0 * 8,        &Kl[0][j0 * 512]);
    gload16(Kbase + (size_t)r1 * HD_ + c1 * 8,        &Kl[0][j1 * 512]);
    gload16(Vbase + (size_t)r0 * S_ + c0 * 8,         &Vl[0][j0 * 512]);
    gload16(Vbase + (size_t)r1 * S_ + c1 * 8,         &Vl[0][j1 * 512]);
    gload16(Kbase + (size_t)(64 + r0) * HD_ + c0 * 8, &Kl[1][j0 * 512]);
    gload16(Kbase + (size_t)(64 + r1) * HD_ + c1 * 8, &Kl[1][j1 * 512]);
    gload16(Vbase + (size_t)r0 * S_ + 64 + c0 * 8,    &Vl[1][j0 * 512]);
    gload16(Vbase + (size_t)r1 * S_ + 64 + c1 * 8,    &Vl[1][j1 * 512]);

    for (int step = 0; step < nsteps; ++step) {
      const int cur = step % 3;
      const int kv0 = step * 64;
      if (step + 1 < nsteps) { asm volatile("s_waitcnt vmcnt(4)" ::: "memory"); }
      else                   { asm volatile("s_waitcnt vmcnt(0)" ::: "memory"); }
      __builtin_amdgcn_s_barrier();
      __builtin_amdgcn_sched_barrier(0);

      if (step + 2 < nsteps) {
        const int nb  = (step + 2) % 3;
        const int nkv = kv0 + 128;
        gload16(Kbase + (size_t)(nkv + r0) * HD_ + c0 * 8, &Kl[nb][j0 * 512]);
        gload16(Kbase + (size_t)(nkv + r1) * HD_ + c1 * 8, &Kl[nb][j1 * 512]);
        gload16(Vbase + (size_t)r0 * S_ + nkv + c0 * 8,    &Vl[nb][j0 * 512]);
        gload16(Vbase + (size_t)r1 * S_ + nkv + c1 * 8,    &Vl[nb][j1 * 512]);
      }

      const u16* Kc = Kl[cur];
      const u16* Vc = Vl[cur];

      bf16x8_t kf0[4], kf1[4];
#pragma unroll
      for (int kt = 0; kt < 4; kt++) {
        const u16* rp = Kc + (kt * 16 + ln) * 64;
        kf0[kt] = *reinterpret_cast<const bf16x8_t*>(rp + ck0 * 8);
        kf1[kt] = *reinterpret_cast<const bf16x8_t*>(rp + ck1 * 8);
      }
      f32x4_t s[2][4];
#pragma unroll
      for (int mt = 0; mt < 2; mt++)
#pragma unroll
        for (int kt = 0; kt < 4; kt++) {
          f32x4_t acc = (f32x4_t){0.f, 0.f, 0.f, 0.f};
          acc = __builtin_amdgcn_mfma_f32_16x16x32_bf16(qf[mt][0], kf0[kt], acc, 0, 0, 0);
          acc = __builtin_amdgcn_mfma_f32_16x16x32_bf16(qf[mt][1], kf1[kt], acc, 0, 0, 0);
          s[mt][kt] = acc;
        }

      bf16x8_t vf0[4], vf1[4];
#pragma unroll
      for (int dt = 0; dt < 4; dt++) {
        const u16* rp = Vc + (dt * 16 + ln) * 64;
        vf0[dt] = *reinterpret_cast<const bf16x8_t*>(rp + ck0 * 8);
        vf1[dt] = *reinterpret_cast<const bf16x8_t*>(rp + ck1 * 8);
      }

      if (kv0 + 63 > qrow0) {
#pragma unroll
        for (int mt = 0; mt < 2; mt++)
#pragma unroll
          for (int kt = 0; kt < 4; kt++)
#pragma unroll
            for (int r = 0; r < 4; r++) {
              int rowg = qrow0 + mt * 16 + quad * 4 + r;
              if (kv0 + kt * 16 + ln > rowg) s[mt][kt][r] = -1e30f;
            }
      }

#pragma unroll
      for (int mt = 0; mt < 2; mt++)
#pragma unroll
        for (int r = 0; r < 4; r++) {
          float p0f = __expf(s[mt][0][r] - MEXP);
          float p1f = __expf(s[mt][1][r] - MEXP);
          float p2f = __expf(s[mt][2][r] - MEXP);
          float p3f = __expf(s[mt][3][r] - MEXP);
          l[mt][r] += (p0f + p1f) + (p2f + p3f);
          ushort4 pk;   // truncation pack (bias cancels in O/l)
          pk.x = (u16)(__float_as_uint(p0f) >> 16);
          pk.y = (u16)(__float_as_uint(p1f) >> 16);
          pk.z = (u16)(__float_as_uint(p2f) >> 16);
          pk.w = (u16)(__float_as_uint(p3f) >> 16);
          *reinterpret_cast<ushort4*>(&Plds[wv][mt][quad * 4 + r][ln * 4]) = pk;
        }

#pragma unroll
      for (int mt = 0; mt < 2; mt++) {
        bf16x8_t pf0 = *reinterpret_cast<const bf16x8_t*>(&Plds[wv][mt][ln][quad * 8]);
        bf16x8_t pf1 = *reinterpret_cast<const bf16x8_t*>(&Plds[wv][mt][ln][32 + quad * 8]);
#pragma unroll
        for (int dt = 0; dt < 4; dt++) {
          O[mt][dt] = __builtin_amdgcn_mfma_f32_16x16x32_bf16(pf0, vf0[dt], O[mt][dt], 0, 0, 0);
          O[mt][dt] = __builtin_amdgcn_mfma_f32_16x16x32_bf16(pf1, vf1[dt], O[mt][dt], 0, 0, 0);
        }
      }
    }

#pragma unroll
    for (int mt = 0; mt < 2; mt++)
#pragma unroll
      for (int r = 0; r < 4; r++) {
        float lv = l[mt][r];
        lv += __shfl_xor(lv, 1);
        lv += __shfl_xor(lv, 2);
        lv += __shfl_xor(lv, 4);
        lv += __shfl_xor(lv, 8);
        float inv = 1.0f / lv;
        int srow = qrow0 + mt * 16 + quad * 4 + r;
        size_t base = ((size_t)b * S_ + srow) * (size_t)(NH_ * HD_) + h * HD_;
#pragma unroll
        for (int dt = 0; dt < 4; dt++)
          Og[base + dt * 16 + ln] = f2bf(O[mt][dt][r] * inv);
      }
  }
}

// ---------------- launch ----------------

extern "C" void kernel_launch(void* const* d_in, const int* in_sizes, int n_in,
                              void* d_out, int out_size, void* d_ws, size_t ws_size,
                              hipStream_t stream) {
  const float* x  = (const float*)d_in[0];
  const int*   pos = (const int*)d_in[1];
  const float* Wq = (const float*)d_in[2];
  const float* bq = (const float*)d_in[3];
  const float* Wk = (const float*)d_in[4];
  const float* bk = (const float*)d_in[5];
  const float* Wv = (const float*)d_in[6];
  const float* bv = (const float*)d_in[7];
  const float* Wo = (const float*)d_in[8];
  float* out = (float*)d_out;

  char* ws = (char*)d_ws;
  u16*   xb    = (u16*)(ws);                     // [4096][2048] bf16   16.8MB
  u16*   Wqkvt = (u16*)(ws + 16777216);          // [3072][2048] bf16   12.6MB
  u16*   Wot   = (u16*)(ws + 29360128);          // [2048][2048] bf16    8.4MB
  float* cosb  = (float*)(ws + 37748736);        // [4096][32] f32
  float* sinb  = (float*)(ws + 38797312);        // [4096][32] f32
  u16*   Qb    = (u16*)(ws + 39845888);          // [B][NH][S][HD]      16.8MB
  u16*   Kb    = (u16*)(ws + 56623104);          // [B][NKV][S][HD]      4.2MB
  u16*   Vtmp  = (u16*)(ws + 60817408);          // [4096][512] bf16     4.2MB
  u16*   Vt    = (u16*)(ws + 65011712);          // [B][NKV][HD][S]      4.2MB (kv-permuted)
  u16*   Og    = (u16*)(ws + 69206016);          // [4096][2048] bf16   16.8MB

  prep_all<<<18944, 256, 0, stream>>>(x, xb, Wq, Wk, Wv, Wqkvt, Wo, Wot,
                                      pos, cosb, sinb);

  gemm256<0><<<dim3(16, 12), 512, 0, stream>>>(xb, Wqkvt, bq, bk, bv, cosb, sinb,
                                               Qb, Kb, Vtmp, nullptr, 0);

  prep_v<<<dim3(32, 16), 256, 0, stream>>>(Vtmp, Vt);

  flash_attn<<<dim3(32, 16), 256, 0, stream>>>(Qb, Kb, Vt, Og);

  gemm256<1><<<dim3(32, 8), 512, 0, stream>>>(Og, Wot, nullptr, nullptr, nullptr,
                                              nullptr, nullptr, nullptr, nullptr, nullptr,
                                              out, 2048);
}

// Round 9
// 283.929 us; speedup vs baseline: 1.1550x; 1.0154x over previous
//
#include <hip/hip_runtime.h>

#define B_   2
#define S_   2048
#define H_   2048
#define NH_  32
#define NKV_ 8
#define HD_  64
#define ROWS (B_*S_)   // 4096
#define MEXP 20.0f

typedef unsigned short u16;
typedef __bf16 bf16x8_t __attribute__((ext_vector_type(8)));
typedef float  f32x4_t  __attribute__((ext_vector_type(4)));

__device__ __forceinline__ u16 f2bf(float f) {
  union { float f; unsigned u; } v; v.f = f;
  unsigned u = v.u;
  u += 0x7FFFu + ((u >> 16) & 1u);
  return (u16)(u >> 16);
}

// async global->LDS, 16B per lane. LDS dest = wave-uniform base + lane*16.
__device__ __forceinline__ void gload16(const u16* g, u16* l) {
  __builtin_amdgcn_global_load_lds((const __attribute__((address_space(1))) void*)g,
                                   (__attribute__((address_space(3))) void*)l, 16, 0, 0);
}

// ---------------- fused input prep: cvt | transpose_wqkv | transpose_w | cossin ----------------
__global__ void prep_all(const float* __restrict__ x, u16* __restrict__ xb,
                         const float* __restrict__ Wq, const float* __restrict__ Wk,
                         const float* __restrict__ Wv, u16* __restrict__ Wqkvt,
                         const float* __restrict__ Wo, u16* __restrict__ Wot,
                         const int* __restrict__ pos,
                         float* __restrict__ cosb, float* __restrict__ sinb) {
  __shared__ float t[32][33];
  int bid = blockIdx.x;
  if (bid < 8192) {
    int i = bid * 256 + threadIdx.x;
    float4 v = reinterpret_cast<const float4*>(x)[i];
    ushort4 o;
    o.x = f2bf(v.x); o.y = f2bf(v.y); o.z = f2bf(v.z); o.w = f2bf(v.w);
    reinterpret_cast<ushort4*>(xb)[i] = o;
    return;
  }
  bid -= 8192;
  const int tx = threadIdx.x & 31, ty = threadIdx.x >> 5;   // (32,8)
  if (bid < 6144) {
    const int bx = bid % 96, by = bid / 96;
    const int k0  = by * 32;
    const int n0g = bx * 32;
    const float* src; int N, n0;
    if (n0g < 2048)      { src = Wq; N = 2048; n0 = n0g; }
    else if (n0g < 2560) { src = Wk; N = 512;  n0 = n0g - 2048; }
    else                 { src = Wv; N = 512;  n0 = n0g - 2560; }
#pragma unroll
    for (int i = 0; i < 32; i += 8)
      t[ty + i][tx] = src[(size_t)(k0 + ty + i) * N + n0 + tx];
    __syncthreads();
#pragma unroll
    for (int i = 0; i < 32; i += 8)
      Wqkvt[(size_t)(n0g + ty + i) * 2048 + k0 + tx] = f2bf(t[tx][ty + i]);
    return;
  }
  bid -= 6144;
  if (bid < 4096) {
    const int bx = bid % 64, by = bid / 64;
    const int k0 = by * 32;
    const int n0 = bx * 32;
#pragma unroll
    for (int i = 0; i < 32; i += 8)
      t[ty + i][tx] = Wo[(size_t)(k0 + ty + i) * 2048 + n0 + tx];
    __syncthreads();
#pragma unroll
    for (int i = 0; i < 32; i += 8)
      Wot[(size_t)(n0 + ty + i) * 2048 + k0 + tx] = f2bf(t[tx][ty + i]);
    return;
  }
  bid -= 4096;
  {
    int tt = bid * 256 + threadIdx.x;   // row*32 + d
    int row = tt >> 5, d = tt & 31;
    int sec = (d < 16) ? 0 : 1;
    float p = (float)pos[sec * ROWS + row];
    float inv_freq = powf(1.0e6f, -(float)d * (1.0f / 32.0f));
    float fr = p * inv_freq;
    float s, c;
    sincosf(fr, &s, &c);
    cosb[tt] = c;
    sinb[tt] = s;
  }
}

// ---------------- BK=64 2-barrier pipelined GEMM (T2+T3+T4+T5) ----------------
// R9: barriers 4->2 per K-tile (MODE 0), 3->2 (MODE 1). Kept barriers:
//  BAR#A: after all waves' bfr MFMAs -> B(kt+2) re-stage of Bs[par] is safe.
//  BAR#B: after counted vmcnt -> publishes staged A(kt+1)/B(kt+1..2).
// Removed barriers were redundant: STG A targets As[par^1] whose readers
// finished before kt-1's BAR#B; MFMA inputs are wave-local lgkm-waited.
// vmcnt ring invariant (both modes): entering kt, queue = B(kt+1) only.

#define BAR() { __builtin_amdgcn_s_barrier(); __builtin_amdgcn_sched_barrier(0); }

#define STG(G, L, RB, h, kt) { \
    const u16* g_ = (G) + (size_t)((RB) + (h) * 128 + srow) * 2048 + (kt) * 64 + sc8; \
    gload16(g_,             (L) + (h) * 8192 + sldo);       \
    gload16(g_ + 8 * 2048,  (L) + (h) * 8192 + sldo + 512); }

#define LDAF(mm) \
    af[0][0] = *reinterpret_cast<const bf16x8_t*>(Asp + rowxA + (mm) * 1024 + cof0); \
    af[0][1] = *reinterpret_cast<const bf16x8_t*>(Asp + rowxA + (mm) * 1024 + cof1); \
    af[1][0] = *reinterpret_cast<const bf16x8_t*>(Asp + rowxA + (mm) * 1024 + 1024 + cof0); \
    af[1][1] = *reinterpret_cast<const bf16x8_t*>(Asp + rowxA + (mm) * 1024 + 1024 + cof1);

#define MFMA8(mb) \
    _Pragma("unroll") \
    for (int n = 0; n < 4; ++n) { \
      acc[(mb)][n]     = __builtin_amdgcn_mfma_f32_16x16x32_bf16(af[0][0], bfr[n][0], acc[(mb)][n], 0, 0, 0); \
      acc[(mb)][n]     = __builtin_amdgcn_mfma_f32_16x16x32_bf16(af[0][1], bfr[n][1], acc[(mb)][n], 0, 0, 0); \
      acc[(mb) + 1][n] = __builtin_amdgcn_mfma_f32_16x16x32_bf16(af[1][0], bfr[n][0], acc[(mb) + 1][n], 0, 0, 0); \
      acc[(mb) + 1][n] = __builtin_amdgcn_mfma_f32_16x16x32_bf16(af[1][1], bfr[n][1], acc[(mb) + 1][n], 0, 0, 0); \
    }

template <int MODE>
__global__ __launch_bounds__(512, 2) void gemm256(
    const u16* __restrict__ A, const u16* __restrict__ Bt,
    const float* __restrict__ bq, const float* __restrict__ bk, const float* __restrict__ bv,
    const float* __restrict__ cosb, const float* __restrict__ sinb,
    u16* __restrict__ Qb, u16* __restrict__ Kb, u16* __restrict__ Vtmp,
    float* __restrict__ Cout, int Nout) {
  constexpr int BMx = (MODE == 0) ? 256 : 128;   // M tile
  constexpr int MF  = BMx / 32;                  // per-wave m-frags (8 or 4)

  const int m0 = blockIdx.x * BMx;
  const int n0 = blockIdx.y * 256;

  __shared__ __align__(16) u16 As[2][BMx * 64];
  __shared__ __align__(16) u16 Bs[2][16384];
  const int tid  = threadIdx.x;
  const int lane = tid & 63;
  const int wv   = tid >> 6;        // 0..7
  const int wr   = wv >> 2;         // 0..1  (M half)
  const int wc   = wv & 3;          // 0..3  (N quarter)
  const int ln   = lane & 15;
  const int quad = lane >> 4;

  const int srow = wv * 16 + (lane >> 3);            // row within half (2nd gload +8)
  const int sc8  = ((lane & 7) ^ (lane >> 3)) * 8;   // pre-swizzled k-chunk (u16)
  const int sldo = wv * 1024;                        // u16 offset of wave slice

  const int rowxA = (wr * (BMx / 2) + ln) * 64;
  const int rowxB = (wc * 64       + ln) * 64;
  const int cof0  = ((quad    ) ^ (ln & 7)) * 8;     // kk=0 chunk = quad
  const int cof1  = ((quad ^ 4) ^ (ln & 7)) * 8;     // kk=1 chunk = 4+quad

  f32x4_t acc[MF][4];
#pragma unroll
  for (int i = 0; i < MF; i++)
#pragma unroll
    for (int j = 0; j < 4; j++)
      acc[i][j] = (f32x4_t){0.f, 0.f, 0.f, 0.f};

  STG(A, As[0], m0, 0, 0);
  if constexpr (MODE == 0) { STG(A, As[0], m0, 1, 0); }
  STG(Bt, Bs[0], n0, 0, 0); STG(Bt, Bs[0], n0, 1, 0);
  STG(Bt, Bs[1], n0, 0, 1); STG(Bt, Bs[1], n0, 1, 1);
  asm volatile("s_waitcnt vmcnt(4)" ::: "memory");
  BAR();

  for (int kt = 0; kt < 32; ++kt) {
    const int par = kt & 1;
    const u16* Asp = As[par];
    const u16* Bsp = Bs[par];
    u16* Asn = As[par ^ 1];
    u16* Bsn = Bs[par];               // B(kt+2) has same parity as B(kt)
    bf16x8_t bfr[4][2], af[2][2];

    if constexpr (MODE == 0) {
      // ---- half 1: bfr + A(m0..m3); stage A(kt+1); consume all bfr ----
#pragma unroll
      for (int n = 0; n < 4; ++n) {
        bfr[n][0] = *reinterpret_cast<const bf16x8_t*>(Bsp + rowxB + n * 1024 + cof0);
        bfr[n][1] = *reinterpret_cast<const bf16x8_t*>(Bsp + rowxB + n * 1024 + cof1);
      }
      LDAF(0);
      if (kt + 1 < 32) { STG(A, Asn, m0, 0, kt + 1); STG(A, Asn, m0, 1, kt + 1); }
      __builtin_amdgcn_s_setprio(1);
      MFMA8(0);
      __builtin_amdgcn_s_setprio(0);
      LDAF(2);
      __builtin_amdgcn_s_setprio(1);
      MFMA8(2);
      __builtin_amdgcn_s_setprio(0);
      BAR();   // BAR#A: all waves consumed bfr -> B(kt+2) re-stage safe

      // ---- half 2: A(m4..m7); stage B(kt+2); counted vmcnt; publish ----
      LDAF(4);
      if (kt + 2 < 32) { STG(Bt, Bsn, n0, 0, kt + 2); STG(Bt, Bsn, n0, 1, kt + 2); }
      __builtin_amdgcn_s_setprio(1);
      MFMA8(4);
      __builtin_amdgcn_s_setprio(0);
      LDAF(6);
      __builtin_amdgcn_s_setprio(1);
      MFMA8(6);
      __builtin_amdgcn_s_setprio(0);
      if (kt + 2 < 32) { asm volatile("s_waitcnt vmcnt(4)" ::: "memory"); }
      else             { asm volatile("s_waitcnt vmcnt(0)" ::: "memory"); }
      BAR();   // BAR#B: publish staged buffers
    } else {
      // ---- half 1: bfr + A(m0,m1); stage A(kt+1); consume bfr ----
#pragma unroll
      for (int n = 0; n < 4; ++n) {
        bfr[n][0] = *reinterpret_cast<const bf16x8_t*>(Bsp + rowxB + n * 1024 + cof0);
        bfr[n][1] = *reinterpret_cast<const bf16x8_t*>(Bsp + rowxB + n * 1024 + cof1);
      }
      LDAF(0);
      if (kt + 1 < 32) { STG(A, Asn, m0, 0, kt + 1); }
      __builtin_amdgcn_s_setprio(1);
      MFMA8(0);
      __builtin_amdgcn_s_setprio(0);
      BAR();   // BAR#A

      // ---- half 2: A(m2,m3); stage B(kt+2); counted vmcnt; publish ----
      LDAF(2);
      if (kt + 2 < 32) { STG(Bt, Bsn, n0, 0, kt + 2); STG(Bt, Bsn, n0, 1, kt + 2); }
      __builtin_amdgcn_s_setprio(1);
      MFMA8(2);
      __builtin_amdgcn_s_setprio(0);
      if (kt + 2 < 32) { asm volatile("s_waitcnt vmcnt(4)" ::: "memory"); }
      else             { asm volatile("s_waitcnt vmcnt(0)" ::: "memory"); }
      BAR();   // BAR#B
    }
  }

  if constexpr (MODE == 0) {
    const int colbase = n0 + wc * 64;   // multiple of 64 -> one head per wave
    if (n0 < 2048) {
      const int hq = colbase >> 6;
#pragma unroll
      for (int i = 0; i < MF; i++) {
        int rw0 = m0 + wr * (BMx / 2) + i * 16 + quad * 4;
#pragma unroll
        for (int j = 0; j < 2; j++) {
          int d = j * 16 + ln;     // < 32
          float b0 = bq[colbase + d];
          float b1 = bq[colbase + d + 32];
#pragma unroll
          for (int r = 0; r < 4; r++) {
            int row = rw0 + r;
            float c  = cosb[row * 32 + d];
            float sn = sinb[row * 32 + d];
            float v0 = acc[i][j][r]     + b0;
            float v1 = acc[i][j + 2][r] + b1;
            int bb = row >> 11, s = row & (S_ - 1);
            size_t base = ((size_t)(bb * NH_ + hq) * S_ + s) * HD_;
            Qb[base + d]      = f2bf((v0 * c - v1 * sn) * 0.125f);
            Qb[base + d + 32] = f2bf((v1 * c + v0 * sn) * 0.125f);
          }
        }
      }
    } else if (n0 < 2560) {
      const int kh = (colbase - 2048) >> 6;
#pragma unroll
      for (int i = 0; i < MF; i++) {
        int rw0 = m0 + wr * (BMx / 2) + i * 16 + quad * 4;
#pragma unroll
        for (int j = 0; j < 2; j++) {
          int d = j * 16 + ln;
          float b0 = bk[(colbase - 2048) + d];
          float b1 = bk[(colbase - 2048) + d + 32];
#pragma unroll
          for (int r = 0; r < 4; r++) {
            int row = rw0 + r;
            float c  = cosb[row * 32 + d];
            float sn = sinb[row * 32 + d];
            float v0 = acc[i][j][r]     + b0;
            float v1 = acc[i][j + 2][r] + b1;
            int bb = row >> 11, s = row & (S_ - 1);
            size_t base = ((size_t)(bb * NKV_ + kh) * S_ + s) * HD_;
            Kb[base + d]      = f2bf(v0 * c - v1 * sn);
            Kb[base + d + 32] = f2bf(v1 * c + v0 * sn);
          }
        }
      }
    } else {
#pragma unroll
      for (int i = 0; i < MF; i++) {
        int rw0 = m0 + wr * (BMx / 2) + i * 16 + quad * 4;
#pragma unroll
        for (int j = 0; j < 4; j++) {
          int cv = colbase - 2560 + j * 16 + ln;
          float bvv = bv[cv];
#pragma unroll
          for (int r = 0; r < 4; r++)
            Vtmp[(size_t)(rw0 + r) * 512 + cv] = f2bf(acc[i][j][r] + bvv);
        }
      }
    }
  } else {
#pragma unroll
    for (int i = 0; i < MF; i++) {
      int row = m0 + wr * (BMx / 2) + i * 16 + quad * 4;
#pragma unroll
      for (int j = 0; j < 4; j++) {
        int col = n0 + wc * 64 + j * 16 + ln;
        float* cp = Cout + (size_t)row * Nout + col;
#pragma unroll
        for (int r = 0; r < 4; r++)
          cp[(size_t)r * Nout] = acc[i][j][r];
      }
    }
  }
}

// V^T with kv-permuted columns from bf16 Vtmp [4096][512].
__global__ void prep_v(const u16* __restrict__ Vtmp, u16* __restrict__ Vt) {
  __shared__ u16 tile[64][65];
  const int sb  = blockIdx.x * 64;
  const int bk  = blockIdx.y;
  const int b   = bk >> 3, kvh = bk & 7;
  const int tx  = threadIdx.x & 63;
  const int ty  = threadIdx.x >> 6;   // 0..3
  const u16* src = Vtmp + (size_t)(b * 2048 + sb) * 512 + kvh * 64;
#pragma unroll
  for (int i = ty; i < 64; i += 4)
    tile[i][tx] = src[(size_t)i * 512 + tx];
  __syncthreads();
  const int sp = sb + (tx & 15) * 4 + (tx >> 4);   // permuted col
  u16* dst = Vt + (size_t)(b * NKV_ + kvh) * HD_ * (size_t)S_;
#pragma unroll
  for (int j = ty; j < 64; j += 4)
    dst[(size_t)j * S_ + sp] = tile[tx][j];
}

// ---------------- causal GQA flash attention (v7) ----------------
__global__ __launch_bounds__(256, 2) void flash_attn(
    const u16* __restrict__ Qb, const u16* __restrict__ Kb, const u16* __restrict__ Vt,
    u16* __restrict__ Og) {
  const int u    = blockIdx.x;        // 0..31
  const int bk   = blockIdx.y;
  const int b    = bk >> 3;
  const int kvh  = bk & 7;
  const int tid  = threadIdx.x;
  const int wv   = tid >> 6;
  const int h    = kvh * 4 + wv;
  const int lane = tid & 63;
  const int ln   = lane & 15;
  const int quad = lane >> 4;

  __shared__ __align__(16) u16 Kl[3][64 * 64];
  __shared__ __align__(16) u16 Vl[3][64 * 64];
  __shared__ __align__(16) u16 Plds[4][2][16][72];

  const u16* Qbase = Qb + ((size_t)(b * NH_ + h) * S_) * HD_;
  const u16* Kbase = Kb + ((size_t)(b * NKV_ + kvh) * S_) * HD_;
  const u16* Vbase = Vt + ((size_t)(b * NKV_ + kvh) * HD_) * S_;

  const int j0 = wv * 2, j1 = wv * 2 + 1;
  const int p0 = j0 * 64 + lane,  p1 = j1 * 64 + lane;
  const int r0 = p0 >> 3,  c0 = (p0 & 7) ^ (r0 & 7);
  const int r1 = p1 >> 3,  c1 = (p1 & 7) ^ (r1 & 7);

  const int sw  = ln & 7;
  const int ck0 = quad ^ sw;
  const int ck1 = ck0 ^ 4;

  const int tlist[2] = {u, 63 - u};

  for (int ti = 0; ti < 2; ++ti) {
    const int t = tlist[ti];
    const int qrow0 = t * 32;
    const int nsteps = t / 2 + 1;

    bf16x8_t qf[2][2];
#pragma unroll
    for (int mt = 0; mt < 2; mt++) {
      qf[mt][0] = *reinterpret_cast<const bf16x8_t*>(
          Qbase + (size_t)(qrow0 + mt * 16 + ln) * HD_ + quad * 8);
      qf[mt][1] = *reinterpret_cast<const bf16x8_t*>(
          Qbase + (size_t)(qrow0 + mt * 16 + ln) * HD_ + 32 + quad * 8);
    }

    f32x4_t O[2][4];
#pragma unroll
    for (int mt = 0; mt < 2; mt++)
#pragma unroll
      for (int dt = 0; dt < 4; dt++)
        O[mt][dt] = (f32x4_t){0.f, 0.f, 0.f, 0.f};
    float l[2][4];
#pragma unroll
    for (int mt = 0; mt < 2; mt++)
#pragma unroll
      for (int r = 0; r < 4; r++) l[mt][r] = 0.f;

    __syncthreads();   // prev-ti readers done; full vmcnt drain (incl. O stores)

    gload16(Kbase + (size_t)r0 * HD_ + c0 * 8,        &Kl[0][j0 * 512]);
    gload16(Kbase + (size_t)r1 * HD_ + c1 * 8,        &Kl[0][j1 * 512]);
    gload16(Vbase + (size_t)r0 * S_ + c0 * 8,         &Vl[0][j0 * 512]);
    gload16(Vbase + (size_t)r1 * S_ + c1 * 8,         &Vl[0][j1 * 512]);
    gload16(Kbase + (size_t)(64 + r0) * HD_ + c0 * 8, &Kl[1][j0 * 512]);
    gload16(Kbase + (size_t)(64 + r1) * HD_ + c1 * 8, &Kl[1][j1 * 512]);
    gload16(Vbase + (size_t)r0 * S_ + 64 + c0 * 8,    &Vl[1][j0 * 512]);
    gload16(Vbase + (size_t)r1 * S_ + 64 + c1 * 8,    &Vl[1][j1 * 512]);

    for (int step = 0; step < nsteps; ++step) {
      const int cur = step % 3;
      const int kv0 = step * 64;
      if (step + 1 < nsteps) { asm volatile("s_waitcnt vmcnt(4)" ::: "memory"); }
      else                   { asm volatile("s_waitcnt vmcnt(0)" ::: "memory"); }
      __builtin_amdgcn_s_barrier();
      __builtin_amdgcn_sched_barrier(0);

      if (step + 2 < nsteps) {
        const int nb  = (step + 2) % 3;
        const int nkv = kv0 + 128;
        gload16(Kbase + (size_t)(nkv + r0) * HD_ + c0 * 8, &Kl[nb][j0 * 512]);
        gload16(Kbase + (size_t)(nkv + r1) * HD_ + c1 * 8, &Kl[nb][j1 * 512]);
        gload16(Vbase + (size_t)r0 * S_ + nkv + c0 * 8,    &Vl[nb][j0 * 512]);
        gload16(Vbase + (size_t)r1 * S_ + nkv + c1 * 8,    &Vl[nb][j1 * 512]);
      }

      const u16* Kc = Kl[cur];
      const u16* Vc = Vl[cur];

      bf16x8_t kf0[4], kf1[4];
#pragma unroll
      for (int kt = 0; kt < 4; kt++) {
        const u16* rp = Kc + (kt * 16 + ln) * 64;
        kf0[kt] = *reinterpret_cast<const bf16x8_t*>(rp + ck0 * 8);
        kf1[kt] = *reinterpret_cast<const bf16x8_t*>(rp + ck1 * 8);
      }
      f32x4_t s[2][4];
#pragma unroll
      for (int mt = 0; mt < 2; mt++)
#pragma unroll
        for (int kt = 0; kt < 4; kt++) {
          f32x4_t acc = (f32x4_t){0.f, 0.f, 0.f, 0.f};
          acc = __builtin_amdgcn_mfma_f32_16x16x32_bf16(qf[mt][0], kf0[kt], acc, 0, 0, 0);
          acc = __builtin_amdgcn_mfma_f32_16x16x32_bf16(qf[mt][1], kf1[kt], acc, 0, 0, 0);
          s[mt][kt] = acc;
        }

      bf16x8_t vf0[4], vf1[4];
#pragma unroll
      for (int dt = 0; dt < 4; dt++) {
        const u16* rp = Vc + (dt * 16 + ln) * 64;
        vf0[dt] = *reinterpret_cast<const bf16x8_t*>(rp + ck0 * 8);
        vf1[dt] = *reinterpret_cast<const bf16x8_t*>(rp + ck1 * 8);
      }

      if (kv0 + 63 > qrow0) {
#pragma unroll
        for (int mt = 0; mt < 2; mt++)
#pragma unroll
          for (int kt = 0; kt < 4; kt++)
#pragma unroll
            for (int r = 0; r < 4; r++) {
              int rowg = qrow0 + mt * 16 + quad * 4 + r;
              if (kv0 + kt * 16 + ln > rowg) s[mt][kt][r] = -1e30f;
            }
      }

#pragma unroll
      for (int mt = 0; mt < 2; mt++)
#pragma unroll
        for (int r = 0; r < 4; r++) {
          float p0f = __expf(s[mt][0][r] - MEXP);
          float p1f = __expf(s[mt][1][r] - MEXP);
          float p2f = __expf(s[mt][2][r] - MEXP);
          float p3f = __expf(s[mt][3][r] - MEXP);
          l[mt][r] += (p0f + p1f) + (p2f + p3f);
          ushort4 pk;   // truncation pack (bias cancels in O/l)
          pk.x = (u16)(__float_as_uint(p0f) >> 16);
          pk.y = (u16)(__float_as_uint(p1f) >> 16);
          pk.z = (u16)(__float_as_uint(p2f) >> 16);
          pk.w = (u16)(__float_as_uint(p3f) >> 16);
          *reinterpret_cast<ushort4*>(&Plds[wv][mt][quad * 4 + r][ln * 4]) = pk;
        }

#pragma unroll
      for (int mt = 0; mt < 2; mt++) {
        bf16x8_t pf0 = *reinterpret_cast<const bf16x8_t*>(&Plds[wv][mt][ln][quad * 8]);
        bf16x8_t pf1 = *reinterpret_cast<const bf16x8_t*>(&Plds[wv][mt][ln][32 + quad * 8]);
#pragma unroll
        for (int dt = 0; dt < 4; dt++) {
          O[mt][dt] = __builtin_amdgcn_mfma_f32_16x16x32_bf16(pf0, vf0[dt], O[mt][dt], 0, 0, 0);
          O[mt][dt] = __builtin_amdgcn_mfma_f32_16x16x32_bf16(pf1, vf1[dt], O[mt][dt], 0, 0, 0);
        }
      }
    }

#pragma unroll
    for (int mt = 0; mt < 2; mt++)
#pragma unroll
      for (int r = 0; r < 4; r++) {
        float lv = l[mt][r];
        lv += __shfl_xor(lv, 1);
        lv += __shfl_xor(lv, 2);
        lv += __shfl_xor(lv, 4);
        lv += __shfl_xor(lv, 8);
        float inv = 1.0f / lv;
        int srow = qrow0 + mt * 16 + quad * 4 + r;
        size_t base = ((size_t)b * S_ + srow) * (size_t)(NH_ * HD_) + h * HD_;
#pragma unroll
        for (int dt = 0; dt < 4; dt++)
          Og[base + dt * 16 + ln] = f2bf(O[mt][dt][r] * inv);
      }
  }
}

// ---------------- launch ----------------

extern "C" void kernel_launch(void* const* d_in, const int* in_sizes, int n_in,
                              void* d_out, int out_size, void* d_ws, size_t ws_size,
                              hipStream_t stream) {
  const float* x  = (const float*)d_in[0];
  const int*   pos = (const int*)d_in[1];
  const float* Wq = (const float*)d_in[2];
  const float* bq = (const float*)d_in[3];
  const float* Wk = (const float*)d_in[4];
  const float* bk = (const float*)d_in[5];
  const float* Wv = (const float*)d_in[6];
  const float* bv = (const float*)d_in[7];
  const float* Wo = (const float*)d_in[8];
  float* out = (float*)d_out;

  char* ws = (char*)d_ws;
  u16*   xb    = (u16*)(ws);                     // [4096][2048] bf16   16.8MB
  u16*   Wqkvt = (u16*)(ws + 16777216);          // [3072][2048] bf16   12.6MB
  u16*   Wot   = (u16*)(ws + 29360128);          // [2048][2048] bf16    8.4MB
  float* cosb  = (float*)(ws + 37748736);        // [4096][32] f32
  float* sinb  = (float*)(ws + 38797312);        // [4096][32] f32
  u16*   Qb    = (u16*)(ws + 39845888);          // [B][NH][S][HD]      16.8MB
  u16*   Kb    = (u16*)(ws + 56623104);          // [B][NKV][S][HD]      4.2MB
  u16*   Vtmp  = (u16*)(ws + 60817408);          // [4096][512] bf16     4.2MB
  u16*   Vt    = (u16*)(ws + 65011712);          // [B][NKV][HD][S]      4.2MB (kv-permuted)
  u16*   Og    = (u16*)(ws + 69206016);          // [4096][2048] bf16   16.8MB

  prep_all<<<18944, 256, 0, stream>>>(x, xb, Wq, Wk, Wv, Wqkvt, Wo, Wot,
                                      pos, cosb, sinb);

  gemm256<0><<<dim3(16, 12), 512, 0, stream>>>(xb, Wqkvt, bq, bk, bv, cosb, sinb,
                                               Qb, Kb, Vtmp, nullptr, 0);

  prep_v<<<dim3(32, 16), 256, 0, stream>>>(Vtmp, Vt);

  flash_attn<<<dim3(32, 16), 256, 0, stream>>>(Qb, Kb, Vt, Og);

  gemm256<1><<<dim3(32, 8), 512, 0, stream>>>(Og, Wot, nullptr, nullptr, nullptr,
                                              nullptr, nullptr, nullptr, nullptr, nullptr,
                                              out, 2048);
}